// Round 1
// baseline (467.668 us; speedup 1.0000x reference)
//
#include <hip/hip_runtime.h>
#include <math.h>

#define BB 128
#define HH 768
#define KQ 32768

constexpr float TINV = 1.0f / 0.07f;

__device__ __forceinline__ unsigned f2key(float f) {
  unsigned u = __float_as_uint(f);
  return (u & 0x80000000u) ? ~u : (u | 0x80000000u);
}
__device__ __forceinline__ float key2f(unsigned k) {
  unsigned u = (k & 0x80000000u) ? (k & 0x7FFFFFFFu) : ~k;
  return __uint_as_float(u);
}
__device__ __forceinline__ unsigned long long shfl_down_u64(unsigned long long v, int o) {
  unsigned lo = (unsigned)v, hi = (unsigned)(v >> 32);
  lo = __shfl_down(lo, o);
  hi = __shfl_down(hi, o);
  return ((unsigned long long)hi << 32) | lo;
}

__global__ void zero_out(float* out) { out[0] = 0.0f; }

// C = act(A[M,Kd] @ W[Kd,N] + bias), BM=BN=64, BK=16, 256 thr, 4x4 micro
template <bool DO_TANH>
__global__ __launch_bounds__(256) void gemm_bias_act(
    const float* __restrict__ A, const float* __restrict__ W,
    const float* __restrict__ bias, float* __restrict__ Cout,
    int M, int N, int Kd) {
  __shared__ float As[16][68];  // [k][m]
  __shared__ float Ws[16][68];  // [k][n]
  const int n0 = blockIdx.x * 64;
  const int m0 = blockIdx.y * 64;
  const int tid = threadIdx.x;
  const int tn = tid & 15, tm = tid >> 4;
  float acc[4][4] = {};
  for (int k0 = 0; k0 < Kd; k0 += 16) {
    {
      const int r = tid >> 2, c = (tid & 3) << 2;
      float4 a4 = *reinterpret_cast<const float4*>(A + (size_t)(m0 + r) * Kd + k0 + c);
      As[c + 0][r] = a4.x; As[c + 1][r] = a4.y; As[c + 2][r] = a4.z; As[c + 3][r] = a4.w;
      const int r2 = tid >> 4, c2 = (tid & 15) << 2;
      float4 w4 = *reinterpret_cast<const float4*>(W + (size_t)(k0 + r2) * N + n0 + c2);
      *reinterpret_cast<float4*>(&Ws[r2][c2]) = w4;
    }
    __syncthreads();
#pragma unroll
    for (int kk = 0; kk < 16; ++kk) {
      float4 a4 = *reinterpret_cast<const float4*>(&As[kk][tm << 2]);
      float4 w4 = *reinterpret_cast<const float4*>(&Ws[kk][tn << 2]);
      float av[4] = {a4.x, a4.y, a4.z, a4.w};
      float wv[4] = {w4.x, w4.y, w4.z, w4.w};
#pragma unroll
      for (int i = 0; i < 4; ++i)
#pragma unroll
        for (int j = 0; j < 4; ++j) acc[i][j] = fmaf(av[i], wv[j], acc[i][j]);
    }
    __syncthreads();
  }
  const float4 b4 = *reinterpret_cast<const float4*>(bias + n0 + (tn << 2));
  const float bv[4] = {b4.x, b4.y, b4.z, b4.w};
#pragma unroll
  for (int i = 0; i < 4; ++i) {
    float ov[4];
#pragma unroll
    for (int j = 0; j < 4; ++j) {
      float v = acc[i][j] + bv[j];
      ov[j] = DO_TANH ? tanhf(v) : v;
    }
    float4 o = make_float4(ov[0], ov[1], ov[2], ov[3]);
    *reinterpret_cast<float4*>(Cout + (size_t)(m0 + (tm << 2) + i) * N + n0 + (tn << 2)) = o;
  }
}

// C[b,k] = sum_h Q[b,h]*FQ[k,h]; BM=128(all batch) x BN=128 queue, BK=32, 8x8 micro
__global__ __launch_bounds__(256) void cos_gemm(
    const float* __restrict__ Qm, const float* __restrict__ FQ, float* __restrict__ C) {
  __shared__ float Qs[32][132];  // [k][b]
  __shared__ float Fs[32][132];  // [k][q]
  const int q0 = blockIdx.x * 128;
  const int tid = threadIdx.x;
  const int tq = tid & 15, tb = tid >> 4;
  float acc[8][8] = {};
  for (int k0 = 0; k0 < HH; k0 += 32) {
    const int r = tid >> 1, s = (tid & 1) << 4;
#pragma unroll
    for (int u = 0; u < 4; ++u) {
      const int c = s + (u << 2);
      float4 v = *reinterpret_cast<const float4*>(Qm + (size_t)r * HH + k0 + c);
      Qs[c + 0][r] = v.x; Qs[c + 1][r] = v.y; Qs[c + 2][r] = v.z; Qs[c + 3][r] = v.w;
      float4 w = *reinterpret_cast<const float4*>(FQ + (size_t)(q0 + r) * HH + k0 + c);
      Fs[c + 0][r] = w.x; Fs[c + 1][r] = w.y; Fs[c + 2][r] = w.z; Fs[c + 3][r] = w.w;
    }
    __syncthreads();
#pragma unroll 4
    for (int kk = 0; kk < 32; ++kk) {
      float4 qa = *reinterpret_cast<const float4*>(&Qs[kk][tb << 3]);
      float4 qb = *reinterpret_cast<const float4*>(&Qs[kk][(tb << 3) + 4]);
      float4 fa = *reinterpret_cast<const float4*>(&Fs[kk][tq << 3]);
      float4 fb = *reinterpret_cast<const float4*>(&Fs[kk][(tq << 3) + 4]);
      float qv[8] = {qa.x, qa.y, qa.z, qa.w, qb.x, qb.y, qb.z, qb.w};
      float fv[8] = {fa.x, fa.y, fa.z, fa.w, fb.x, fb.y, fb.z, fb.w};
#pragma unroll
      for (int i = 0; i < 8; ++i)
#pragma unroll
        for (int j = 0; j < 8; ++j) acc[i][j] = fmaf(qv[i], fv[j], acc[i][j]);
    }
    __syncthreads();
  }
#pragma unroll
  for (int i = 0; i < 8; ++i) {
    float* dst = C + (size_t)((tb << 3) + i) * KQ + q0 + (tq << 3);
    *reinterpret_cast<float4*>(dst) = make_float4(acc[i][0], acc[i][1], acc[i][2], acc[i][3]);
    *reinterpret_cast<float4*>(dst + 4) = make_float4(acc[i][4], acc[i][5], acc[i][6], acc[i][7]);
  }
}

__global__ __launch_bounds__(256) void l2norm_rows(const float* __restrict__ Y,
                                                   float* __restrict__ Qm) {
  const int b = blockIdx.x, tid = threadIdx.x;
  __shared__ float sh[4];
  __shared__ float snorm;
  float ss = 0.f;
  for (int h = tid; h < HH; h += 256) {
    float v = Y[(size_t)b * HH + h];
    ss = fmaf(v, v, ss);
  }
  for (int o = 32; o; o >>= 1) ss += __shfl_down(ss, o);
  const int lane = tid & 63, wid = tid >> 6;
  if (lane == 0) sh[wid] = ss;
  __syncthreads();
  if (tid == 0) snorm = 1.0f / sqrtf(sh[0] + sh[1] + sh[2] + sh[3]);
  __syncthreads();
  const float rs = snorm;
  for (int h = tid; h < HH; h += 256) Qm[(size_t)b * HH + h] = Y[(size_t)b * HH + h] * rs;
}

__global__ __launch_bounds__(256) void cls_loss_kernel(
    const float* __restrict__ H1, const float* __restrict__ W2,
    const float* __restrict__ b2, const int* __restrict__ labels,
    float* __restrict__ out) {
  const int b = blockIdx.x, tid = threadIdx.x;
  __shared__ float sh0[4], sh1[4];
  float p0 = 0.f, p1 = 0.f;
  for (int h = tid; h < HH; h += 256) {
    float v = H1[(size_t)b * HH + h];
    p0 = fmaf(v, W2[h * 2 + 0], p0);
    p1 = fmaf(v, W2[h * 2 + 1], p1);
  }
  for (int o = 32; o; o >>= 1) {
    p0 += __shfl_down(p0, o);
    p1 += __shfl_down(p1, o);
  }
  const int lane = tid & 63, wid = tid >> 6;
  if (lane == 0) { sh0[wid] = p0; sh1[wid] = p1; }
  __syncthreads();
  if (tid == 0) {
    float l0 = sh0[0] + sh0[1] + sh0[2] + sh0[3] + b2[0];
    float l1 = sh1[0] + sh1[1] + sh1[2] + sh1[3] + b2[1];
    float mx = fmaxf(l0, l1), mn = fminf(l0, l1);
    float lse = mx + log1pf(__expf(mn - mx));
    float ce = lse - (labels[b] ? l1 : l0);
    atomicAdd(out, 0.9f * ce * (1.0f / 128.0f));
  }
}

__global__ __launch_bounds__(1024) void counts_kernel(const int* __restrict__ labels,
                                                      const int* __restrict__ lq,
                                                      int* __restrict__ m_out) {
  const int tid = threadIdx.x;
  __shared__ int sh[16];
  __shared__ int has[2];
  int c = 0;
  for (int k = tid; k < KQ; k += 1024) c += lq[k];
  for (int o = 32; o; o >>= 1) c += __shfl_down(c, o);
  const int lane = tid & 63, wid = tid >> 6;
  if (tid < 2) has[tid] = 0;
  __syncthreads();
  if (lane == 0) sh[wid] = c;
  if (tid < BB) has[labels[tid]] = 1;  // same-value writes, benign
  __syncthreads();
  if (tid == 0) {
    int n1 = 0;
    for (int w = 0; w < 16; ++w) n1 += sh[w];
    int n0 = KQ - n1;
    int mm = 0x7fffffff;
    if (has[0] && n0 < mm) mm = n0;
    if (has[1] && n1 < mm) mm = n1;
    *m_out = mm;
  }
}

// Per row: f(p) = lse(p/T, log E) - p/T summed over pos ranks [0,25) and [m-25,m).
// E = sum over ALL negs of exp(neg/T) (excluded tail < 1e-6 relative, see analysis).
__global__ __launch_bounds__(1024) void select_kernel(
    const float* __restrict__ Cm, const int* __restrict__ labels,
    const int* __restrict__ lq, const int* __restrict__ m_ptr,
    float* __restrict__ out) {
  const int b = blockIdx.x;
  const int tid = threadIdx.x;
  const int lane = tid & 63, wid = tid >> 6;
  const float* __restrict__ row = Cm + (size_t)b * KQ;
  const int lab = labels[b];
  const int m = *m_ptr;

  __shared__ unsigned posmask[KQ / 32];
  __shared__ float redf[16];
  __shared__ unsigned long long redc[16];
  __shared__ float redf3[16][4];
  __shared__ unsigned bc[3];
  __shared__ float shv[2];

  // pass 0: posmask + max over negs
  float mx = -3.0e38f;
  {
    unsigned bits = 0u;
    const int base = tid << 5;
#pragma unroll
    for (int j = 0; j < 32; ++j) {
      const int isp = (lq[base + j] == lab);
      bits |= (unsigned)isp << j;
      if (!isp) mx = fmaxf(mx, row[base + j]);
    }
    posmask[tid] = bits;
  }
  for (int o = 32; o; o >>= 1) mx = fmaxf(mx, __shfl_down(mx, o));
  if (lane == 0) redf[wid] = mx;
  __syncthreads();
  if (tid == 0) {
    float v = redf[0];
    for (int w = 1; w < 16; ++w) v = fmaxf(v, redf[w]);
    shv[0] = v;
  }
  __syncthreads();
  const float maxneg = shv[0];

  // pass Z: sum exp((neg - maxneg)/T)
  float z = 0.f;
  for (int i = tid; i < (KQ >> 2); i += 1024) {
    const int k = i << 2;
    float4 v = *reinterpret_cast<const float4*>(row + k);
    unsigned bits = (posmask[k >> 5] >> (k & 31)) & 0xFu;
    if (!(bits & 1u)) z += __expf((v.x - maxneg) * TINV);
    if (!(bits & 2u)) z += __expf((v.y - maxneg) * TINV);
    if (!(bits & 4u)) z += __expf((v.z - maxneg) * TINV);
    if (!(bits & 8u)) z += __expf((v.w - maxneg) * TINV);
  }
  for (int o = 32; o; o >>= 1) z += __shfl_down(z, o);
  if (lane == 0) redf[wid] = z;
  __syncthreads();
  if (tid == 0) {
    float v = 0.f;
    for (int w = 0; w < 16; ++w) v += redf[w];
    shv[1] = maxneg * TINV + logf(v);  // log E
  }
  __syncthreads();
  const float cE = shv[1];

  // 3-way lockstep 32-bit binary search for keys at descending ranks 24, m-26, m-1
  unsigned a0 = 0u, a1 = 0u, a2 = 0u;
  const unsigned tg0 = 25u, tg1 = (unsigned)(m - 25), tg2 = (unsigned)m;
  for (int bit = 31; bit >= 0; --bit) {
    const unsigned mskb = 1u << bit;
    const unsigned c0 = a0 | mskb, c1 = a1 | mskb, c2 = a2 | mskb;
    unsigned n0c = 0, n1c = 0, n2c = 0;
    for (int i = tid; i < (KQ >> 2); i += 1024) {
      const int k = i << 2;
      float4 v = *reinterpret_cast<const float4*>(row + k);
      unsigned bits = (posmask[k >> 5] >> (k & 31)) & 0xFu;
      float vv[4] = {v.x, v.y, v.z, v.w};
#pragma unroll
      for (int j = 0; j < 4; ++j) {
        if (bits & (1u << j)) {
          const unsigned key = f2key(vv[j]);
          n0c += (key >= c0);
          n1c += (key >= c1);
          n2c += (key >= c2);
        }
      }
    }
    unsigned long long pk = (unsigned long long)n0c |
                            ((unsigned long long)n1c << 20) |
                            ((unsigned long long)n2c << 40);
    for (int o = 32; o; o >>= 1) pk += shfl_down_u64(pk, o);
    if (lane == 0) redc[wid] = pk;
    __syncthreads();
    if (tid == 0) {
      unsigned long long t = 0ull;
      for (int w = 0; w < 16; ++w) t += redc[w];
      unsigned t0 = (unsigned)(t & 0xFFFFFu);
      unsigned t1 = (unsigned)((t >> 20) & 0xFFFFFu);
      unsigned t2 = (unsigned)((t >> 40) & 0xFFFFFu);
      bc[0] = (t0 >= tg0) ? c0 : a0;
      bc[1] = (t1 >= tg1) ? c1 : a1;
      bc[2] = (t2 >= tg2) ? c2 : a2;
    }
    __syncthreads();
    a0 = bc[0]; a1 = bc[1]; a2 = bc[2];
  }

  // gather: strictly-greater sums/counts per threshold (a0 >= a1 >= a2 in key space)
  float s0 = 0.f, s1 = 0.f, s2 = 0.f;
  unsigned q0c = 0, q1c = 0, q2c = 0;
  for (int i = tid; i < (KQ >> 2); i += 1024) {
    const int k = i << 2;
    float4 v = *reinterpret_cast<const float4*>(row + k);
    unsigned bits = (posmask[k >> 5] >> (k & 31)) & 0xFu;
    float vv[4] = {v.x, v.y, v.z, v.w};
#pragma unroll
    for (int j = 0; j < 4; ++j) {
      if (bits & (1u << j)) {
        const unsigned key = f2key(vv[j]);
        if (key > a2) {
          const float a = vv[j] * TINV;
          const float d = cE - a;
          const float fv = fmaxf(d, 0.f) + log1pf(__expf(-fabsf(d)));
          s2 += fv; ++q2c;
          if (key > a1) { s1 += fv; ++q1c; }
          if (key > a0) { s0 += fv; ++q0c; }
        }
      }
    }
  }
  unsigned long long pc = (unsigned long long)q0c |
                          ((unsigned long long)q1c << 20) |
                          ((unsigned long long)q2c << 40);
  for (int o = 32; o; o >>= 1) {
    s0 += __shfl_down(s0, o);
    s1 += __shfl_down(s1, o);
    s2 += __shfl_down(s2, o);
    pc = pc + shfl_down_u64(pc, o);
  }
  if (lane == 0) {
    redf3[wid][0] = s0; redf3[wid][1] = s1; redf3[wid][2] = s2;
    redc[wid] = pc;
  }
  __syncthreads();
  if (tid == 0) {
    float S0 = 0.f, S1 = 0.f, S2 = 0.f;
    unsigned long long t = 0ull;
    for (int w = 0; w < 16; ++w) {
      S0 += redf3[w][0]; S1 += redf3[w][1]; S2 += redf3[w][2];
      t += redc[w];
    }
    const float C0 = (float)(unsigned)(t & 0xFFFFFu);
    const float C1 = (float)(unsigned)((t >> 20) & 0xFFFFFu);
    const float C2 = (float)(unsigned)((t >> 40) & 0xFFFFFu);
    auto fval = [&](unsigned kk) {
      const float vvv = key2f(kk);
      const float a = vvv * TINV;
      const float d = cE - a;
      return fmaxf(d, 0.f) + log1pf(__expf(-fabsf(d)));
    };
    const float f0 = fval(a0), fhi = fval(a1), flo = fval(a2);
    const float top25 = S0 + (25.0f - C0) * f0;                 // Sum_top(25)
    const float sum_m = S2 + ((float)m - C2) * flo;             // Sum_top(m)
    const float sum_m25 = S1 + ((float)(m - 25) - C1) * fhi;    // Sum_top(m-25)
    const float total = top25 + (sum_m - sum_m25);
    atomicAdd(out, 0.1f * total * (1.0f / 6400.0f));
  }
}

extern "C" void kernel_launch(void* const* d_in, const int* in_sizes, int n_in,
                              void* d_out, int out_size, void* d_ws, size_t ws_size,
                              hipStream_t stream) {
  const float* pooled = (const float*)d_in[0];
  const int* labels = (const int*)d_in[1];
  const float* fq = (const float*)d_in[2];
  const int* lq = (const int*)d_in[3];
  const float* cls_dw = (const float*)d_in[4];
  const float* cls_db = (const float*)d_in[5];
  const float* cls_ow = (const float*)d_in[6];
  const float* cls_ob = (const float*)d_in[7];
  const float* con_dw = (const float*)d_in[8];
  const float* con_db = (const float*)d_in[9];
  const float* con_ow = (const float*)d_in[10];
  const float* con_ob = (const float*)d_in[11];
  float* out = (float*)d_out;

  float* ws = (float*)d_ws;
  float* H1 = ws;                      // 128*768
  float* H2 = ws + 98304;              // 128*768
  float* Y = ws + 2 * 98304;           // 128*768
  float* Qn = ws + 3 * 98304;          // 128*768
  float* C = ws + 4 * 98304;           // 128*32768
  int* mptr = (int*)(ws + 4 * 98304 + (size_t)BB * KQ);

  zero_out<<<1, 1, 0, stream>>>(out);
  gemm_bias_act<true><<<dim3(12, 2), 256, 0, stream>>>(pooled, cls_dw, cls_db, H1, BB, HH, HH);
  gemm_bias_act<true><<<dim3(12, 2), 256, 0, stream>>>(pooled, con_dw, con_db, H2, BB, HH, HH);
  gemm_bias_act<false><<<dim3(12, 2), 256, 0, stream>>>(H2, con_ow, con_ob, Y, BB, HH, HH);
  l2norm_rows<<<128, 256, 0, stream>>>(Y, Qn);
  cls_loss_kernel<<<128, 256, 0, stream>>>(H1, cls_ow, cls_ob, labels, out);
  counts_kernel<<<1, 1024, 0, stream>>>(labels, lq, mptr);
  cos_gemm<<<KQ / 128, 256, 0, stream>>>(Qn, fq, C);
  select_kernel<<<128, 1024, 0, stream>>>(C, labels, lq, mptr, out);
}

// Round 2
// 325.946 us; speedup vs baseline: 1.4348x; 1.4348x over previous
//
#include <hip/hip_runtime.h>
#include <math.h>

#define BB 128
#define HH 768
#define KQ 32768
#define PCAP 18432  // max positives per row we stage in LDS (16384 + 22 sigma)

constexpr float TINV = 1.0f / 0.07f;

__device__ __forceinline__ unsigned f2key(float f) {
  unsigned u = __float_as_uint(f);
  return u ^ (unsigned)(((int)u >> 31) | 0x80000000);
}
__device__ __forceinline__ float key2f(unsigned k) {
  unsigned u = (k & 0x80000000u) ? (k & 0x7FFFFFFFu) : ~k;
  return __uint_as_float(u);
}
__device__ __forceinline__ unsigned long long shfl_down_u64(unsigned long long v, int o) {
  unsigned lo = (unsigned)v, hi = (unsigned)(v >> 32);
  lo = __shfl_down(lo, o);
  hi = __shfl_down(hi, o);
  return ((unsigned long long)hi << 32) | lo;
}

__global__ void zero_out(float* out) { out[0] = 0.0f; }

// C = act(A[M,Kd] @ W[Kd,N] + bias), BM=BN=64, BK=16, 256 thr, 4x4 micro
template <bool DO_TANH>
__global__ __launch_bounds__(256) void gemm_bias_act(
    const float* __restrict__ A, const float* __restrict__ W,
    const float* __restrict__ bias, float* __restrict__ Cout,
    int M, int N, int Kd) {
  __shared__ float As[16][68];  // [k][m]
  __shared__ float Ws[16][68];  // [k][n]
  const int n0 = blockIdx.x * 64;
  const int m0 = blockIdx.y * 64;
  const int tid = threadIdx.x;
  const int tn = tid & 15, tm = tid >> 4;
  float acc[4][4] = {};
  for (int k0 = 0; k0 < Kd; k0 += 16) {
    {
      const int r = tid >> 2, c = (tid & 3) << 2;
      float4 a4 = *reinterpret_cast<const float4*>(A + (size_t)(m0 + r) * Kd + k0 + c);
      As[c + 0][r] = a4.x; As[c + 1][r] = a4.y; As[c + 2][r] = a4.z; As[c + 3][r] = a4.w;
      const int r2 = tid >> 4, c2 = (tid & 15) << 2;
      float4 w4 = *reinterpret_cast<const float4*>(W + (size_t)(k0 + r2) * N + n0 + c2);
      *reinterpret_cast<float4*>(&Ws[r2][c2]) = w4;
    }
    __syncthreads();
#pragma unroll
    for (int kk = 0; kk < 16; ++kk) {
      float4 a4 = *reinterpret_cast<const float4*>(&As[kk][tm << 2]);
      float4 w4 = *reinterpret_cast<const float4*>(&Ws[kk][tn << 2]);
      float av[4] = {a4.x, a4.y, a4.z, a4.w};
      float wv[4] = {w4.x, w4.y, w4.z, w4.w};
#pragma unroll
      for (int i = 0; i < 4; ++i)
#pragma unroll
        for (int j = 0; j < 4; ++j) acc[i][j] = fmaf(av[i], wv[j], acc[i][j]);
    }
    __syncthreads();
  }
  const float4 b4 = *reinterpret_cast<const float4*>(bias + n0 + (tn << 2));
  const float bv[4] = {b4.x, b4.y, b4.z, b4.w};
#pragma unroll
  for (int i = 0; i < 4; ++i) {
    float ov[4];
#pragma unroll
    for (int j = 0; j < 4; ++j) {
      float v = acc[i][j] + bv[j];
      ov[j] = DO_TANH ? tanhf(v) : v;
    }
    float4 o = make_float4(ov[0], ov[1], ov[2], ov[3]);
    *reinterpret_cast<float4*>(Cout + (size_t)(m0 + (tm << 2) + i) * N + n0 + (tn << 2)) = o;
  }
}

// C[b,k] = sum_h Q[b,h]*FQ[k,h]; BM=128(all batch) x BN=128 queue, BK=32, 8x8 micro
__global__ __launch_bounds__(256) void cos_gemm(
    const float* __restrict__ Qm, const float* __restrict__ FQ, float* __restrict__ C) {
  __shared__ float Qs[32][132];  // [k][b]
  __shared__ float Fs[32][132];  // [k][q]
  const int q0 = blockIdx.x * 128;
  const int tid = threadIdx.x;
  const int tq = tid & 15, tb = tid >> 4;
  float acc[8][8] = {};
  for (int k0 = 0; k0 < HH; k0 += 32) {
    const int r = tid >> 1, s = (tid & 1) << 4;
#pragma unroll
    for (int u = 0; u < 4; ++u) {
      const int c = s + (u << 2);
      float4 v = *reinterpret_cast<const float4*>(Qm + (size_t)r * HH + k0 + c);
      Qs[c + 0][r] = v.x; Qs[c + 1][r] = v.y; Qs[c + 2][r] = v.z; Qs[c + 3][r] = v.w;
      float4 w = *reinterpret_cast<const float4*>(FQ + (size_t)(q0 + r) * HH + k0 + c);
      Fs[c + 0][r] = w.x; Fs[c + 1][r] = w.y; Fs[c + 2][r] = w.z; Fs[c + 3][r] = w.w;
    }
    __syncthreads();
#pragma unroll 4
    for (int kk = 0; kk < 32; ++kk) {
      float4 qa = *reinterpret_cast<const float4*>(&Qs[kk][tb << 3]);
      float4 qb = *reinterpret_cast<const float4*>(&Qs[kk][(tb << 3) + 4]);
      float4 fa = *reinterpret_cast<const float4*>(&Fs[kk][tq << 3]);
      float4 fb = *reinterpret_cast<const float4*>(&Fs[kk][(tq << 3) + 4]);
      float qv[8] = {qa.x, qa.y, qa.z, qa.w, qb.x, qb.y, qb.z, qb.w};
      float fv[8] = {fa.x, fa.y, fa.z, fa.w, fb.x, fb.y, fb.z, fb.w};
#pragma unroll
      for (int i = 0; i < 8; ++i)
#pragma unroll
        for (int j = 0; j < 8; ++j) acc[i][j] = fmaf(qv[i], fv[j], acc[i][j]);
    }
    __syncthreads();
  }
#pragma unroll
  for (int i = 0; i < 8; ++i) {
    float* dst = C + (size_t)((tb << 3) + i) * KQ + q0 + (tq << 3);
    *reinterpret_cast<float4*>(dst) = make_float4(acc[i][0], acc[i][1], acc[i][2], acc[i][3]);
    *reinterpret_cast<float4*>(dst + 4) = make_float4(acc[i][4], acc[i][5], acc[i][6], acc[i][7]);
  }
}

__global__ __launch_bounds__(256) void l2norm_rows(const float* __restrict__ Y,
                                                   float* __restrict__ Qm) {
  const int b = blockIdx.x, tid = threadIdx.x;
  __shared__ float sh[4];
  __shared__ float snorm;
  float ss = 0.f;
  for (int h = tid; h < HH; h += 256) {
    float v = Y[(size_t)b * HH + h];
    ss = fmaf(v, v, ss);
  }
  for (int o = 32; o; o >>= 1) ss += __shfl_down(ss, o);
  const int lane = tid & 63, wid = tid >> 6;
  if (lane == 0) sh[wid] = ss;
  __syncthreads();
  if (tid == 0) snorm = 1.0f / sqrtf(sh[0] + sh[1] + sh[2] + sh[3]);
  __syncthreads();
  const float rs = snorm;
  for (int h = tid; h < HH; h += 256) Qm[(size_t)b * HH + h] = Y[(size_t)b * HH + h] * rs;
}

__global__ __launch_bounds__(256) void cls_loss_kernel(
    const float* __restrict__ H1, const float* __restrict__ W2,
    const float* __restrict__ b2, const int* __restrict__ labels,
    float* __restrict__ out) {
  const int b = blockIdx.x, tid = threadIdx.x;
  __shared__ float sh0[4], sh1[4];
  float p0 = 0.f, p1 = 0.f;
  for (int h = tid; h < HH; h += 256) {
    float v = H1[(size_t)b * HH + h];
    p0 = fmaf(v, W2[h * 2 + 0], p0);
    p1 = fmaf(v, W2[h * 2 + 1], p1);
  }
  for (int o = 32; o; o >>= 1) {
    p0 += __shfl_down(p0, o);
    p1 += __shfl_down(p1, o);
  }
  const int lane = tid & 63, wid = tid >> 6;
  if (lane == 0) { sh0[wid] = p0; sh1[wid] = p1; }
  __syncthreads();
  if (tid == 0) {
    float l0 = sh0[0] + sh0[1] + sh0[2] + sh0[3] + b2[0];
    float l1 = sh1[0] + sh1[1] + sh1[2] + sh1[3] + b2[1];
    float mx = fmaxf(l0, l1), mn = fminf(l0, l1);
    float lse = mx + log1pf(__expf(mn - mx));
    float ce = lse - (labels[b] ? l1 : l0);
    atomicAdd(out, 0.9f * ce * (1.0f / 128.0f));
  }
}

// Also builds qmask: bit=1 iff label_queue[k]==1 (32 elements per thread/word).
__global__ __launch_bounds__(1024) void counts_kernel(const int* __restrict__ labels,
                                                      const int* __restrict__ lq,
                                                      int* __restrict__ m_out,
                                                      unsigned* __restrict__ qmask) {
  const int tid = threadIdx.x;
  __shared__ int sh[16];
  __shared__ int has[2];
  unsigned mask = 0u;
  const int base = tid << 5;
#pragma unroll
  for (int j = 0; j < 32; ++j) mask |= (unsigned)(lq[base + j] != 0) << j;
  qmask[tid] = mask;
  int c = __popc(mask);
  for (int o = 32; o; o >>= 1) c += __shfl_down(c, o);
  const int lane = tid & 63, wid = tid >> 6;
  if (tid < 2) has[tid] = 0;
  __syncthreads();
  if (lane == 0) sh[wid] = c;
  if (tid < BB) has[labels[tid]] = 1;  // same-value writes, benign
  __syncthreads();
  if (tid == 0) {
    int n1 = 0;
    for (int w = 0; w < 16; ++w) n1 += sh[w];
    int n0 = KQ - n1;
    int mm = 0x7fffffff;
    if (has[0] && n0 < mm) mm = n0;
    if (has[1] && n1 < mm) mm = n1;
    *m_out = mm;
  }
}

// One global pass (neg-lse + compact positive KEYS to LDS), then 32 LDS-resident
// binary-search passes (1 barrier each) + 1 LDS gather pass.
__global__ __launch_bounds__(1024) void select_kernel(
    const float* __restrict__ Cm, const int* __restrict__ labels,
    const unsigned* __restrict__ qmask, const int* __restrict__ m_ptr,
    float* __restrict__ out) {
  const int b = blockIdx.x;
  const int tid = threadIdx.x;
  const int lane = tid & 63, wid = tid >> 6;
  const float* __restrict__ row = Cm + (size_t)b * KQ;
  const int lab = labels[b];
  const int m = *m_ptr;

  __shared__ __align__(16) unsigned poskeys[PCAP];
  __shared__ unsigned long long accv[33];  // 32 search passes + 1 gather counts
  __shared__ float redm[16], reds[16];
  __shared__ float gs0, gsm, s_logE;
  __shared__ int s_cnt;

  if (tid < 33) accv[tid] = 0ull;
  if (tid == 0) { s_cnt = 0; gs0 = 0.f; gsm = 0.f; }
  __syncthreads();

  // ---------- Pass A: read row once; neg online-lse + compact positive keys ----------
  const unsigned qm = qmask[tid];
  const unsigned pmask = lab ? qm : ~qm;
  const int base = tid << 5;
  float va[32];
#pragma unroll
  for (int u = 0; u < 8; ++u) {
    float4 v = *reinterpret_cast<const float4*>(row + base + (u << 2));
    va[(u << 2) + 0] = v.x; va[(u << 2) + 1] = v.y;
    va[(u << 2) + 2] = v.z; va[(u << 2) + 3] = v.w;
  }
  float mneg = -3.0e38f, sneg = 0.f;
#pragma unroll
  for (int j = 0; j < 32; ++j) {
    const float a = va[j] * TINV;
    if (!((pmask >> j) & 1u)) mneg = fmaxf(mneg, a);
  }
#pragma unroll
  for (int j = 0; j < 32; ++j) {
    const float a = va[j] * TINV;
    if (!((pmask >> j) & 1u)) sneg += __expf(a - mneg);
  }
  // wave-combine (m,s)
#pragma unroll
  for (int o = 32; o; o >>= 1) {
    const float mo = __shfl_down(mneg, o), so = __shfl_down(sneg, o);
    const float M = fmaxf(mneg, mo);
    sneg = sneg * __expf(mneg - M) + so * __expf(mo - M);
    mneg = M;
  }
  if (lane == 0) { redm[wid] = mneg; reds[wid] = sneg; }

  // compact positives: wave prefix-sum + one LDS atomic per wave
  const int np = __popc(pmask);
  unsigned incl = (unsigned)np;
#pragma unroll
  for (int o = 1; o < 64; o <<= 1) {
    const unsigned t = __shfl_up(incl, o);
    if (lane >= o) incl += t;
  }
  const unsigned excl = incl - (unsigned)np;
  const unsigned wtot = __shfl(incl, 63);
  unsigned wbase = 0u;
  if (lane == 63) wbase = (unsigned)atomicAdd(&s_cnt, (int)wtot);
  wbase = __shfl(wbase, 63);
  const int ofs = (int)(wbase + excl);
  if (ofs + np <= PCAP) {
#pragma unroll
    for (int j = 0; j < 32; ++j) {
      if ((pmask >> j) & 1u)
        poskeys[ofs + __popc(pmask & ((1u << j) - 1u))] = f2key(va[j]);
    }
  }
  __syncthreads();

  const int P = s_cnt;
  if (tid == 0) {
    float M = redm[0], S = 0.f;
    for (int w = 1; w < 16; ++w) M = fmaxf(M, redm[w]);
    for (int w = 0; w < 16; ++w) S += reds[w] * __expf(redm[w] - M);
    s_logE = M + logf(S);  // log sum_neg exp(v/T)
  }
  if (tid < ((4 - (P & 3)) & 3)) poskeys[P + tid] = 0u;  // pad (key 0 < any real key)
  __syncthreads();
  const float cE = s_logE;
  const int P4c = (P + 3) >> 2;
  const uint4* __restrict__ pk4 = reinterpret_cast<const uint4*>(poskeys);

  // ---------- 3-way lockstep binary search over LDS keys ----------
  unsigned a0 = 0u, a1 = 0u, a2 = 0u;
  const unsigned tg0 = 25u, tg1 = (unsigned)(m - 25), tg2 = (unsigned)m;
  for (int bit = 31; bit >= 0; --bit) {
    const unsigned mskb = 1u << bit;
    const unsigned c0 = a0 | mskb, c1 = a1 | mskb, c2 = a2 | mskb;
    unsigned n0c = 0, n1c = 0, n2c = 0;
    for (int i = tid; i < P4c; i += 1024) {
      const uint4 kv = pk4[i];
      n0c += (kv.x >= c0) + (kv.y >= c0) + (kv.z >= c0) + (kv.w >= c0);
      n1c += (kv.x >= c1) + (kv.y >= c1) + (kv.z >= c1) + (kv.w >= c1);
      n2c += (kv.x >= c2) + (kv.y >= c2) + (kv.z >= c2) + (kv.w >= c2);
    }
    unsigned long long pk = (unsigned long long)n0c |
                            ((unsigned long long)n1c << 20) |
                            ((unsigned long long)n2c << 40);
#pragma unroll
    for (int o = 32; o; o >>= 1) pk += shfl_down_u64(pk, o);
    if (lane == 0) atomicAdd(&accv[31 - bit], pk);
    __syncthreads();
    const unsigned long long t = accv[31 - bit];
    a0 = ((unsigned)(t & 0xFFFFFu) >= tg0) ? c0 : a0;
    a1 = ((unsigned)((t >> 20) & 0xFFFFFu) >= tg1) ? c1 : a1;
    a2 = ((unsigned)((t >> 40) & 0xFFFFFu) >= tg2) ? c2 : a2;
  }

  // ---------- gather: f only for ranks <=25 and (m-25, m]; counts elsewhere ----------
  float s0 = 0.f, sm = 0.f;
  unsigned q0c = 0, q1c = 0, q2c = 0;
  for (int i = tid; i < P4c; i += 1024) {
    const uint4 kv = pk4[i];
    const unsigned ks[4] = {kv.x, kv.y, kv.z, kv.w};
#pragma unroll
    for (int j = 0; j < 4; ++j) {
      const unsigned k = ks[j];
      if (k > a2) {
        ++q2c;
        const bool top = (k > a0), mid = (k <= a1);
        if (k > a1) ++q1c;
        if (top) ++q0c;
        if (top || mid) {
          const float a = key2f(k) * TINV;
          const float d = cE - a;
          const float fv = fmaxf(d, 0.f) + log1pf(__expf(-fabsf(d)));
          if (top) s0 += fv;
          if (mid) sm += fv;
        }
      }
    }
  }
  unsigned long long pc = (unsigned long long)q0c |
                          ((unsigned long long)q1c << 20) |
                          ((unsigned long long)q2c << 40);
#pragma unroll
  for (int o = 32; o; o >>= 1) {
    s0 += __shfl_down(s0, o);
    sm += __shfl_down(sm, o);
    pc += shfl_down_u64(pc, o);
  }
  if (lane == 0) {
    atomicAdd(&gs0, s0);
    atomicAdd(&gsm, sm);
    atomicAdd(&accv[32], pc);
  }
  __syncthreads();
  if (tid == 0) {
    const unsigned long long t = accv[32];
    const float C0 = (float)(unsigned)(t & 0xFFFFFu);
    const float C1 = (float)(unsigned)((t >> 20) & 0xFFFFFu);
    const float C2 = (float)(unsigned)((t >> 40) & 0xFFFFFu);
    auto fval = [&](unsigned kk) {
      const float a = key2f(kk) * TINV;
      const float d = cE - a;
      return fmaxf(d, 0.f) + log1pf(__expf(-fabsf(d)));
    };
    const float f0 = fval(a0), f1 = fval(a1), f2 = fval(a2);
    const float top25 = gs0 + (25.0f - C0) * f0;
    const float mid = gsm + ((float)m - C2) * f2 - ((float)(m - 25) - C1) * f1;
    atomicAdd(out, 0.1f * (top25 + mid) * (1.0f / 6400.0f));
  }
}

extern "C" void kernel_launch(void* const* d_in, const int* in_sizes, int n_in,
                              void* d_out, int out_size, void* d_ws, size_t ws_size,
                              hipStream_t stream) {
  const float* pooled = (const float*)d_in[0];
  const int* labels = (const int*)d_in[1];
  const float* fq = (const float*)d_in[2];
  const int* lq = (const int*)d_in[3];
  const float* cls_dw = (const float*)d_in[4];
  const float* cls_db = (const float*)d_in[5];
  const float* cls_ow = (const float*)d_in[6];
  const float* cls_ob = (const float*)d_in[7];
  const float* con_dw = (const float*)d_in[8];
  const float* con_db = (const float*)d_in[9];
  const float* con_ow = (const float*)d_in[10];
  const float* con_ob = (const float*)d_in[11];
  float* out = (float*)d_out;

  float* ws = (float*)d_ws;
  float* H1 = ws;                      // 128*768
  float* H2 = ws + 98304;              // 128*768
  float* Y = ws + 2 * 98304;           // 128*768
  float* Qn = ws + 3 * 98304;          // 128*768
  float* C = ws + 4 * 98304;           // 128*32768
  int* mptr = (int*)(ws + 4 * 98304 + (size_t)BB * KQ);
  unsigned* qmask = (unsigned*)(mptr + 1);  // 1024 words

  zero_out<<<1, 1, 0, stream>>>(out);
  gemm_bias_act<true><<<dim3(12, 2), 256, 0, stream>>>(pooled, cls_dw, cls_db, H1, BB, HH, HH);
  gemm_bias_act<true><<<dim3(12, 2), 256, 0, stream>>>(pooled, con_dw, con_db, H2, BB, HH, HH);
  gemm_bias_act<false><<<dim3(12, 2), 256, 0, stream>>>(H2, con_ow, con_ob, Y, BB, HH, HH);
  l2norm_rows<<<128, 256, 0, stream>>>(Y, Qn);
  cls_loss_kernel<<<128, 256, 0, stream>>>(H1, cls_ow, cls_ob, labels, out);
  counts_kernel<<<1, 1024, 0, stream>>>(labels, lq, mptr, qmask);
  cos_gemm<<<KQ / 128, 256, 0, stream>>>(Qn, fq, C);
  select_kernel<<<128, 1024, 0, stream>>>(C, labels, qmask, mptr, out);
}

// Round 3
// 220.396 us; speedup vs baseline: 2.1219x; 1.4789x over previous
//
#include <hip/hip_runtime.h>
#include <math.h>

#define BB 128
#define HH 768
#define KQ 32768
#define PCAP 18432  // max positives per row staged in LDS

constexpr float TINV = 1.0f / 0.07f;

typedef __attribute__((ext_vector_type(8))) short short8;
typedef __attribute__((ext_vector_type(4))) float f32x4;
typedef __attribute__((address_space(3))) void lds_void;
typedef const __attribute__((address_space(1))) void gbl_void;

__device__ __forceinline__ unsigned short f2bf(float f) {
  unsigned u = __float_as_uint(f);
  unsigned r = u + 0x7FFFu + ((u >> 16) & 1u);  // RNE
  return (unsigned short)(r >> 16);
}
__device__ __forceinline__ float bf2f(unsigned short h) {
  return __uint_as_float(((unsigned)h) << 16);
}
__device__ __forceinline__ unsigned f2key(float f) {
  unsigned u = __float_as_uint(f);
  return u ^ (unsigned)(((int)u >> 31) | 0x80000000);
}
__device__ __forceinline__ float key2f(unsigned k) {
  unsigned u = (k & 0x80000000u) ? (k & 0x7FFFFFFFu) : ~k;
  return __uint_as_float(u);
}
__device__ __forceinline__ unsigned long long shfl_down_u64(unsigned long long v, int o) {
  unsigned lo = (unsigned)v, hi = (unsigned)(v >> 32);
  lo = __shfl_down(lo, o);
  hi = __shfl_down(hi, o);
  return ((unsigned long long)hi << 32) | lo;
}
__device__ __forceinline__ void gl16(const unsigned short* g, unsigned short* l) {
  __builtin_amdgcn_global_load_lds((gbl_void*)g, (lds_void*)l, 16, 0, 0);
}
__device__ __forceinline__ void cvt4(const float4 v, unsigned short* ph, unsigned short* pl) {
  const unsigned short h0 = f2bf(v.x), h1 = f2bf(v.y), h2 = f2bf(v.z), h3 = f2bf(v.w);
  const unsigned short l0 = f2bf(v.x - bf2f(h0)), l1 = f2bf(v.y - bf2f(h1));
  const unsigned short l2 = f2bf(v.z - bf2f(h2)), l3 = f2bf(v.w - bf2f(h3));
  *reinterpret_cast<ushort4*>(ph) = make_ushort4(h0, h1, h2, h3);
  *reinterpret_cast<ushort4*>(pl) = make_ushort4(l0, l1, l2, l3);
}

__global__ void zero_out(float* out) { out[0] = 0.0f; }

// C = act(A[M,Kd] @ W[Kd,N] + bias), BM=BN=32, BK=16, 256 thr, 2x2 micro
template <bool DO_TANH>
__global__ __launch_bounds__(256) void gemm_bias_act32(
    const float* __restrict__ A, const float* __restrict__ W,
    const float* __restrict__ bias, float* __restrict__ Cout, int N, int Kd) {
  __shared__ float As[16][33];  // [k][m]
  __shared__ float Ws[16][36];  // [k][n]
  const int n0 = blockIdx.x * 32;
  const int m0 = blockIdx.y * 32;
  const int tid = threadIdx.x;
  const int tn = tid & 15, tm = tid >> 4;
  float acc[2][2] = {};
  for (int k0 = 0; k0 < Kd; k0 += 16) {
    if (tid < 128) {
      const int r = tid >> 2, c = (tid & 3) << 2;
      float4 a4 = *reinterpret_cast<const float4*>(A + (size_t)(m0 + r) * Kd + k0 + c);
      As[c + 0][r] = a4.x; As[c + 1][r] = a4.y; As[c + 2][r] = a4.z; As[c + 3][r] = a4.w;
    } else {
      const int t2 = tid - 128;
      const int r2 = t2 >> 3, c2 = (t2 & 7) << 2;
      float4 w4 = *reinterpret_cast<const float4*>(W + (size_t)(k0 + r2) * N + n0 + c2);
      *reinterpret_cast<float4*>(&Ws[r2][c2]) = w4;
    }
    __syncthreads();
#pragma unroll
    for (int kk = 0; kk < 16; ++kk) {
      const float a0 = As[kk][tm * 2], a1 = As[kk][tm * 2 + 1];
      const float w0 = Ws[kk][tn * 2], w1 = Ws[kk][tn * 2 + 1];
      acc[0][0] = fmaf(a0, w0, acc[0][0]); acc[0][1] = fmaf(a0, w1, acc[0][1]);
      acc[1][0] = fmaf(a1, w0, acc[1][0]); acc[1][1] = fmaf(a1, w1, acc[1][1]);
    }
    __syncthreads();
  }
  const float b0 = bias[n0 + tn * 2], b1 = bias[n0 + tn * 2 + 1];
#pragma unroll
  for (int i = 0; i < 2; ++i) {
    float v0 = acc[i][0] + b0, v1 = acc[i][1] + b1;
    if (DO_TANH) { v0 = tanhf(v0); v1 = tanhf(v1); }
    float* dst = Cout + (size_t)(m0 + tm * 2 + i) * N + n0 + tn * 2;
    dst[0] = v0; dst[1] = v1;
  }
}

// cos GEMM via bf16-split MFMA. BM=128(all batch) x BN=64, BK=32, 256 thr, dbuf LDS.
__global__ __launch_bounds__(256, 2) void cos_gemm_mfma(
    const unsigned short* __restrict__ qh, const unsigned short* __restrict__ ql,
    const float* __restrict__ FQ, float* __restrict__ C) {
  __shared__ unsigned short Ah[2][128 * 32];
  __shared__ unsigned short Al[2][128 * 32];
  __shared__ unsigned short Bh[2][64 * 32];
  __shared__ unsigned short Bl[2][64 * 32];
  const int tid = threadIdx.x;
  const int lane = tid & 63, wid = tid >> 6;
  const int q0 = blockIdx.x * 64;

  // A staging: wave wid stages rows [wid*32, wid*32+32); pre-swizzled global src.
  int aldsb[2], asrc[2];
#pragma unroll
  for (int j = 0; j < 2; ++j) {
    const int row = wid * 32 + j * 16 + (lane >> 2);
    const int kg = (lane & 3) ^ ((row >> 1) & 3);
    aldsb[j] = (wid * 32 + j * 16) * 32;  // uniform lds ushort base
    asrc[j] = row * HH + kg * 8;          // per-lane global ushort offset (+k0)
  }
  // B staging: thread covers rows br0 and br0+32, 4 floats at bc4*4.
  const int br0 = tid >> 3, bc4 = tid & 7;
  const size_t bsrc0 = (size_t)(q0 + br0) * HH + bc4 * 4;
  const size_t bsrc1 = bsrc0 + (size_t)32 * HH;
  const int bkb = bc4 >> 1, bhalf = (bc4 & 1) * 4;
  const int bdst0 = br0 * 32 + ((bkb ^ ((br0 >> 1) & 3)) << 3) + bhalf;
  const int br1 = br0 + 32;
  const int bdst1 = br1 * 32 + ((bkb ^ ((br1 >> 1) & 3)) << 3) + bhalf;

  // compute-side fragment offsets (swizzled)
  const int wm = wid >> 1, wn = wid & 1;
  int aoff[4], boff[2];
#pragma unroll
  for (int m = 0; m < 4; ++m) {
    const int row = wm * 64 + m * 16 + (lane & 15);
    const int kb = (lane >> 4) ^ ((row >> 1) & 3);
    aoff[m] = row * 32 + kb * 8;
  }
#pragma unroll
  for (int n = 0; n < 2; ++n) {
    const int col = wn * 32 + n * 16 + (lane & 15);
    const int kb = (lane >> 4) ^ ((col >> 1) & 3);
    boff[n] = col * 32 + kb * 8;
  }

  f32x4 acc[4][2];
#pragma unroll
  for (int m = 0; m < 4; ++m)
#pragma unroll
    for (int n = 0; n < 2; ++n) acc[m][n] = (f32x4){0.f, 0.f, 0.f, 0.f};

  // prologue: stage k0=0 into buffer 0
  {
    const float4 s0 = *reinterpret_cast<const float4*>(FQ + bsrc0);
    const float4 s1 = *reinterpret_cast<const float4*>(FQ + bsrc1);
#pragma unroll
    for (int j = 0; j < 2; ++j) {
      gl16(qh + asrc[j], &Ah[0][aldsb[j]]);
      gl16(ql + asrc[j], &Al[0][aldsb[j]]);
    }
    cvt4(s0, &Bh[0][bdst0], &Bl[0][bdst0]);
    cvt4(s1, &Bh[0][bdst1], &Bl[0][bdst1]);
    __syncthreads();
  }

  for (int t = 0; t < 24; ++t) {
    const int cb = t & 1, nb = cb ^ 1;
    float4 s0, s1;
    if (t < 23) {
      const int k0 = (t + 1) * 32;
      s0 = *reinterpret_cast<const float4*>(FQ + bsrc0 + k0);
      s1 = *reinterpret_cast<const float4*>(FQ + bsrc1 + k0);
#pragma unroll
      for (int j = 0; j < 2; ++j) {
        gl16(qh + k0 + asrc[j], &Ah[nb][aldsb[j]]);
        gl16(ql + k0 + asrc[j], &Al[nb][aldsb[j]]);
      }
    }
    short8 ah[4], al[4], bh[2], bl[2];
#pragma unroll
    for (int m = 0; m < 4; ++m) {
      ah[m] = *reinterpret_cast<const short8*>(&Ah[cb][aoff[m]]);
      al[m] = *reinterpret_cast<const short8*>(&Al[cb][aoff[m]]);
    }
#pragma unroll
    for (int n = 0; n < 2; ++n) {
      bh[n] = *reinterpret_cast<const short8*>(&Bh[cb][boff[n]]);
      bl[n] = *reinterpret_cast<const short8*>(&Bl[cb][boff[n]]);
    }
#pragma unroll
    for (int m = 0; m < 4; ++m)
#pragma unroll
      for (int n = 0; n < 2; ++n) {
        acc[m][n] = __builtin_amdgcn_mfma_f32_16x16x32_bf16(ah[m], bh[n], acc[m][n], 0, 0, 0);
        acc[m][n] = __builtin_amdgcn_mfma_f32_16x16x32_bf16(al[m], bh[n], acc[m][n], 0, 0, 0);
        acc[m][n] = __builtin_amdgcn_mfma_f32_16x16x32_bf16(ah[m], bl[n], acc[m][n], 0, 0, 0);
      }
    if (t < 23) {
      cvt4(s0, &Bh[nb][bdst0], &Bl[nb][bdst0]);
      cvt4(s1, &Bh[nb][bdst1], &Bl[nb][bdst1]);
    }
    __syncthreads();
  }

  // epilogue: C[row][col], row=(lane>>4)*4+reg (+m*16+wm*64), col=lane&15 (+n*16+wn*32)
  const int crow = wm * 64 + (lane >> 4) * 4;
  const int ccol = q0 + wn * 32 + (lane & 15);
#pragma unroll
  for (int m = 0; m < 4; ++m)
#pragma unroll
    for (int n = 0; n < 2; ++n)
#pragma unroll
      for (int r = 0; r < 4; ++r)
        C[(size_t)(crow + m * 16 + r) * KQ + ccol + n * 16] = acc[m][n][r];
}

// L2-normalize rows of Y and emit bf16 hi/lo split.
__global__ __launch_bounds__(256) void l2norm_split(const float* __restrict__ Y,
                                                    unsigned short* __restrict__ qh,
                                                    unsigned short* __restrict__ ql) {
  const int b = blockIdx.x, tid = threadIdx.x;
  __shared__ float sh[4];
  __shared__ float snorm;
  float ss = 0.f;
  for (int h = tid; h < HH; h += 256) {
    const float v = Y[(size_t)b * HH + h];
    ss = fmaf(v, v, ss);
  }
  for (int o = 32; o; o >>= 1) ss += __shfl_down(ss, o);
  const int lane = tid & 63, wid = tid >> 6;
  if (lane == 0) sh[wid] = ss;
  __syncthreads();
  if (tid == 0) snorm = 1.0f / sqrtf(sh[0] + sh[1] + sh[2] + sh[3]);
  __syncthreads();
  const float rs = snorm;
  for (int h = tid; h < HH; h += 256) {
    const float q = Y[(size_t)b * HH + h] * rs;
    const unsigned short hi = f2bf(q);
    qh[(size_t)b * HH + h] = hi;
    ql[(size_t)b * HH + h] = f2bf(q - bf2f(hi));
  }
}

__global__ __launch_bounds__(256) void cls_loss_kernel(
    const float* __restrict__ H1, const float* __restrict__ W2,
    const float* __restrict__ b2, const int* __restrict__ labels,
    float* __restrict__ out) {
  const int b = blockIdx.x, tid = threadIdx.x;
  __shared__ float sh0[4], sh1[4];
  float p0 = 0.f, p1 = 0.f;
  for (int h = tid; h < HH; h += 256) {
    const float v = H1[(size_t)b * HH + h];
    p0 = fmaf(v, W2[h * 2 + 0], p0);
    p1 = fmaf(v, W2[h * 2 + 1], p1);
  }
  for (int o = 32; o; o >>= 1) {
    p0 += __shfl_down(p0, o);
    p1 += __shfl_down(p1, o);
  }
  const int lane = tid & 63, wid = tid >> 6;
  if (lane == 0) { sh0[wid] = p0; sh1[wid] = p1; }
  __syncthreads();
  if (tid == 0) {
    const float l0 = sh0[0] + sh0[1] + sh0[2] + sh0[3] + b2[0];
    const float l1 = sh1[0] + sh1[1] + sh1[2] + sh1[3] + b2[1];
    const float mx = fmaxf(l0, l1), mn = fminf(l0, l1);
    const float lse = mx + log1pf(__expf(mn - mx));
    const float ce = lse - (labels[b] ? l1 : l0);
    atomicAdd(out, 0.9f * ce * (1.0f / 128.0f));
  }
}

__global__ __launch_bounds__(1024) void counts_kernel(const int* __restrict__ labels,
                                                      const int* __restrict__ lq,
                                                      int* __restrict__ m_out,
                                                      unsigned* __restrict__ qmask) {
  const int tid = threadIdx.x;
  __shared__ int sh[16];
  __shared__ int has[2];
  unsigned mask = 0u;
  const int base = tid << 5;
#pragma unroll
  for (int j = 0; j < 32; ++j) mask |= (unsigned)(lq[base + j] != 0) << j;
  qmask[tid] = mask;
  int c = __popc(mask);
  for (int o = 32; o; o >>= 1) c += __shfl_down(c, o);
  const int lane = tid & 63, wid = tid >> 6;
  if (tid < 2) has[tid] = 0;
  __syncthreads();
  if (lane == 0) sh[wid] = c;
  if (tid < BB) has[labels[tid]] = 1;
  __syncthreads();
  if (tid == 0) {
    int n1 = 0;
    for (int w = 0; w < 16; ++w) n1 += sh[w];
    const int n0 = KQ - n1;
    int mm = 0x7fffffff;
    if (has[0] && n0 < mm) mm = n0;
    if (has[1] && n1 < mm) mm = n1;
    *m_out = mm;
  }
}

// One global pass (neg-lse + compact positive keys to LDS), then 32 LDS-resident
// binary-search passes (1 barrier each) + 1 LDS gather pass.
__global__ __launch_bounds__(1024) void select_kernel(
    const float* __restrict__ Cm, const int* __restrict__ labels,
    const unsigned* __restrict__ qmask, const int* __restrict__ m_ptr,
    float* __restrict__ out) {
  const int b = blockIdx.x;
  const int tid = threadIdx.x;
  const int lane = tid & 63, wid = tid >> 6;
  const float* __restrict__ row = Cm + (size_t)b * KQ;
  const int lab = labels[b];
  const int m = *m_ptr;

  __shared__ __align__(16) unsigned poskeys[PCAP];
  __shared__ unsigned long long accv[33];
  __shared__ float redm[16], reds[16];
  __shared__ float gs0, gsm, s_logE;
  __shared__ int s_cnt;

  if (tid < 33) accv[tid] = 0ull;
  if (tid == 0) { s_cnt = 0; gs0 = 0.f; gsm = 0.f; }
  __syncthreads();

  const unsigned qm = qmask[tid];
  const unsigned pmask = lab ? qm : ~qm;
  const int base = tid << 5;
  float va[32];
#pragma unroll
  for (int u = 0; u < 8; ++u) {
    const float4 v = *reinterpret_cast<const float4*>(row + base + (u << 2));
    va[(u << 2) + 0] = v.x; va[(u << 2) + 1] = v.y;
    va[(u << 2) + 2] = v.z; va[(u << 2) + 3] = v.w;
  }
  float mneg = -3.0e38f, sneg = 0.f;
#pragma unroll
  for (int j = 0; j < 32; ++j) {
    const float a = va[j] * TINV;
    if (!((pmask >> j) & 1u)) mneg = fmaxf(mneg, a);
  }
#pragma unroll
  for (int j = 0; j < 32; ++j) {
    const float a = va[j] * TINV;
    if (!((pmask >> j) & 1u)) sneg += __expf(a - mneg);
  }
#pragma unroll
  for (int o = 32; o; o >>= 1) {
    const float mo = __shfl_down(mneg, o), so = __shfl_down(sneg, o);
    const float M = fmaxf(mneg, mo);
    sneg = sneg * __expf(mneg - M) + so * __expf(mo - M);
    mneg = M;
  }
  if (lane == 0) { redm[wid] = mneg; reds[wid] = sneg; }

  const int np = __popc(pmask);
  unsigned incl = (unsigned)np;
#pragma unroll
  for (int o = 1; o < 64; o <<= 1) {
    const unsigned t = __shfl_up(incl, o);
    if (lane >= o) incl += t;
  }
  const unsigned excl = incl - (unsigned)np;
  const unsigned wtot = __shfl(incl, 63);
  unsigned wbase = 0u;
  if (lane == 63) wbase = (unsigned)atomicAdd(&s_cnt, (int)wtot);
  wbase = __shfl(wbase, 63);
  const int ofs = (int)(wbase + excl);
  if (ofs + np <= PCAP) {
#pragma unroll
    for (int j = 0; j < 32; ++j) {
      if ((pmask >> j) & 1u)
        poskeys[ofs + __popc(pmask & ((1u << j) - 1u))] = f2key(va[j]);
    }
  }
  __syncthreads();

  const int P = s_cnt;
  if (tid == 0) {
    float M = redm[0], S = 0.f;
    for (int w = 1; w < 16; ++w) M = fmaxf(M, redm[w]);
    for (int w = 0; w < 16; ++w) S += reds[w] * __expf(redm[w] - M);
    s_logE = M + logf(S);
  }
  if (tid < ((4 - (P & 3)) & 3)) poskeys[P + tid] = 0u;
  __syncthreads();
  const float cE = s_logE;
  const int P4c = (P + 3) >> 2;
  const uint4* __restrict__ pk4 = reinterpret_cast<const uint4*>(poskeys);

  unsigned a0 = 0u, a1 = 0u, a2 = 0u;
  const unsigned tg0 = 25u, tg1 = (unsigned)(m - 25), tg2 = (unsigned)m;
  for (int bit = 31; bit >= 0; --bit) {
    const unsigned mskb = 1u << bit;
    const unsigned c0 = a0 | mskb, c1 = a1 | mskb, c2 = a2 | mskb;
    unsigned n0c = 0, n1c = 0, n2c = 0;
    for (int i = tid; i < P4c; i += 1024) {
      const uint4 kv = pk4[i];
      n0c += (kv.x >= c0) + (kv.y >= c0) + (kv.z >= c0) + (kv.w >= c0);
      n1c += (kv.x >= c1) + (kv.y >= c1) + (kv.z >= c1) + (kv.w >= c1);
      n2c += (kv.x >= c2) + (kv.y >= c2) + (kv.z >= c2) + (kv.w >= c2);
    }
    unsigned long long pk = (unsigned long long)n0c |
                            ((unsigned long long)n1c << 20) |
                            ((unsigned long long)n2c << 40);
#pragma unroll
    for (int o = 32; o; o >>= 1) pk += shfl_down_u64(pk, o);
    if (lane == 0) atomicAdd(&accv[31 - bit], pk);
    __syncthreads();
    const unsigned long long t = accv[31 - bit];
    a0 = ((unsigned)(t & 0xFFFFFu) >= tg0) ? c0 : a0;
    a1 = ((unsigned)((t >> 20) & 0xFFFFFu) >= tg1) ? c1 : a1;
    a2 = ((unsigned)((t >> 40) & 0xFFFFFu) >= tg2) ? c2 : a2;
  }

  float s0 = 0.f, sm = 0.f;
  unsigned q0c = 0, q1c = 0, q2c = 0;
  for (int i = tid; i < P4c; i += 1024) {
    const uint4 kv = pk4[i];
    const unsigned ks[4] = {kv.x, kv.y, kv.z, kv.w};
#pragma unroll
    for (int j = 0; j < 4; ++j) {
      const unsigned k = ks[j];
      if (k > a2) {
        ++q2c;
        const bool top = (k > a0), mid = (k <= a1);
        if (k > a1) ++q1c;
        if (top) ++q0c;
        if (top || mid) {
          const float a = key2f(k) * TINV;
          const float d = cE - a;
          const float fv = fmaxf(d, 0.f) + log1pf(__expf(-fabsf(d)));
          if (top) s0 += fv;
          if (mid) sm += fv;
        }
      }
    }
  }
  unsigned long long pc = (unsigned long long)q0c |
                          ((unsigned long long)q1c << 20) |
                          ((unsigned long long)q2c << 40);
#pragma unroll
  for (int o = 32; o; o >>= 1) {
    s0 += __shfl_down(s0, o);
    sm += __shfl_down(sm, o);
    pc += shfl_down_u64(pc, o);
  }
  if (lane == 0) {
    atomicAdd(&gs0, s0);
    atomicAdd(&gsm, sm);
    atomicAdd(&accv[32], pc);
  }
  __syncthreads();
  if (tid == 0) {
    const unsigned long long t = accv[32];
    const float C0 = (float)(unsigned)(t & 0xFFFFFu);
    const float C1 = (float)(unsigned)((t >> 20) & 0xFFFFFu);
    const float C2 = (float)(unsigned)((t >> 40) & 0xFFFFFu);
    auto fval = [&](unsigned kk) {
      const float a = key2f(kk) * TINV;
      const float d = cE - a;
      return fmaxf(d, 0.f) + log1pf(__expf(-fabsf(d)));
    };
    const float f0 = fval(a0), f1 = fval(a1), f2 = fval(a2);
    const float top25 = gs0 + (25.0f - C0) * f0;
    const float mid = gsm + ((float)m - C2) * f2 - ((float)(m - 25) - C1) * f1;
    atomicAdd(out, 0.1f * (top25 + mid) * (1.0f / 6400.0f));
  }
}

extern "C" void kernel_launch(void* const* d_in, const int* in_sizes, int n_in,
                              void* d_out, int out_size, void* d_ws, size_t ws_size,
                              hipStream_t stream) {
  const float* pooled = (const float*)d_in[0];
  const int* labels = (const int*)d_in[1];
  const float* fq = (const float*)d_in[2];
  const int* lq = (const int*)d_in[3];
  const float* cls_dw = (const float*)d_in[4];
  const float* cls_db = (const float*)d_in[5];
  const float* cls_ow = (const float*)d_in[6];
  const float* cls_ob = (const float*)d_in[7];
  const float* con_dw = (const float*)d_in[8];
  const float* con_db = (const float*)d_in[9];
  const float* con_ow = (const float*)d_in[10];
  const float* con_ob = (const float*)d_in[11];
  float* out = (float*)d_out;

  float* ws = (float*)d_ws;
  float* H1 = ws;                                        // 128*768 f32
  float* H2 = ws + 98304;                                // 128*768 f32
  float* Y = ws + 2 * 98304;                             // 128*768 f32
  unsigned short* qh = (unsigned short*)(ws + 3 * 98304);         // 128*768 bf16
  unsigned short* ql = (unsigned short*)(ws + 3 * 98304 + 49152); // 128*768 bf16
  float* C = ws + 4 * 98304;                             // 128*32768 f32
  int* mptr = (int*)(ws + 4 * 98304 + (size_t)BB * KQ);
  unsigned* qmask = (unsigned*)(mptr + 1);               // 1024 words

  zero_out<<<1, 1, 0, stream>>>(out);
  gemm_bias_act32<true><<<dim3(24, 4), 256, 0, stream>>>(pooled, cls_dw, cls_db, H1, HH, HH);
  gemm_bias_act32<true><<<dim3(24, 4), 256, 0, stream>>>(pooled, con_dw, con_db, H2, HH, HH);
  gemm_bias_act32<false><<<dim3(24, 4), 256, 0, stream>>>(H2, con_ow, con_ob, Y, HH, HH);
  l2norm_split<<<128, 256, 0, stream>>>(Y, qh, ql);
  cls_loss_kernel<<<128, 256, 0, stream>>>(H1, cls_ow, cls_ob, labels, out);
  counts_kernel<<<1, 1024, 0, stream>>>(labels, lq, mptr, qmask);
  cos_gemm_mfma<<<KQ / 64, 256, 0, stream>>>(qh, ql, fq, C);
  select_kernel<<<128, 1024, 0, stream>>>(C, labels, qmask, mptr, out);
}

// Round 4
// 157.489 us; speedup vs baseline: 2.9695x; 1.3994x over previous
//
#include <hip/hip_runtime.h>
#include <math.h>

#define BB 128
#define HH 768
#define KQ 32768
#define PCAP 18432  // max positives per row staged in LDS
#define NB 4096     // histogram bins
#define CCAP 512    // candidate cap per target bin

constexpr float TINV = 1.0f / 0.07f;

typedef __attribute__((ext_vector_type(8))) short short8;
typedef __attribute__((ext_vector_type(4))) float f32x4;
typedef __attribute__((address_space(3))) void lds_void;
typedef const __attribute__((address_space(1))) void gbl_void;

__device__ __forceinline__ unsigned short f2bf(float f) {
  unsigned u = __float_as_uint(f);
  unsigned r = u + 0x7FFFu + ((u >> 16) & 1u);  // RNE
  return (unsigned short)(r >> 16);
}
__device__ __forceinline__ float bf2f(unsigned short h) {
  return __uint_as_float(((unsigned)h) << 16);
}
__device__ __forceinline__ unsigned f2key(float f) {
  unsigned u = __float_as_uint(f);
  return u ^ (unsigned)(((int)u >> 31) | 0x80000000);
}
__device__ __forceinline__ float key2f(unsigned k) {
  unsigned u = (k & 0x80000000u) ? (k & 0x7FFFFFFFu) : ~k;
  return __uint_as_float(u);
}
__device__ __forceinline__ unsigned long long shfl_down_u64(unsigned long long v, int o) {
  unsigned lo = (unsigned)v, hi = (unsigned)(v >> 32);
  lo = __shfl_down(lo, o);
  hi = __shfl_down(hi, o);
  return ((unsigned long long)hi << 32) | lo;
}
__device__ __forceinline__ void gl16(const unsigned short* g, unsigned short* l) {
  __builtin_amdgcn_global_load_lds((gbl_void*)g, (lds_void*)l, 16, 0, 0);
}
__device__ __forceinline__ void cvt4(const float4 v, unsigned short* ph, unsigned short* pl) {
  const unsigned short h0 = f2bf(v.x), h1 = f2bf(v.y), h2 = f2bf(v.z), h3 = f2bf(v.w);
  const unsigned short l0 = f2bf(v.x - bf2f(h0)), l1 = f2bf(v.y - bf2f(h1));
  const unsigned short l2 = f2bf(v.z - bf2f(h2)), l3 = f2bf(v.w - bf2f(h3));
  *reinterpret_cast<ushort4*>(ph) = make_ushort4(h0, h1, h2, h3);
  *reinterpret_cast<ushort4*>(pl) = make_ushort4(l0, l1, l2, l3);
}

__global__ void zero_out(float* out) { out[0] = 0.0f; }

// C = act(A[M,Kd] @ W[Kd,N] + bias), BM=BN=32, BK=32, 256 thr, 2x2 micro
template <bool DO_TANH>
__global__ __launch_bounds__(256) void gemm_bias_act32(
    const float* __restrict__ A, const float* __restrict__ W,
    const float* __restrict__ bias, float* __restrict__ Cout, int N, int Kd) {
  __shared__ float As[32][33];  // [k][m]
  __shared__ float Ws[32][36];  // [k][n]
  const int n0 = blockIdx.x * 32;
  const int m0 = blockIdx.y * 32;
  const int tid = threadIdx.x;
  const int tn = tid & 15, tm = tid >> 4;
  const int r = tid >> 3, c = (tid & 7) << 2;
  float acc[2][2] = {};
  for (int k0 = 0; k0 < Kd; k0 += 32) {
    const float4 a4 = *reinterpret_cast<const float4*>(A + (size_t)(m0 + r) * Kd + k0 + c);
    As[c + 0][r] = a4.x; As[c + 1][r] = a4.y; As[c + 2][r] = a4.z; As[c + 3][r] = a4.w;
    const float4 w4 = *reinterpret_cast<const float4*>(W + (size_t)(k0 + r) * N + n0 + c);
    *reinterpret_cast<float4*>(&Ws[r][c]) = w4;
    __syncthreads();
#pragma unroll
    for (int kk = 0; kk < 32; ++kk) {
      const float a0 = As[kk][tm * 2], a1 = As[kk][tm * 2 + 1];
      const float w0 = Ws[kk][tn * 2], w1 = Ws[kk][tn * 2 + 1];
      acc[0][0] = fmaf(a0, w0, acc[0][0]); acc[0][1] = fmaf(a0, w1, acc[0][1]);
      acc[1][0] = fmaf(a1, w0, acc[1][0]); acc[1][1] = fmaf(a1, w1, acc[1][1]);
    }
    __syncthreads();
  }
  const float b0 = bias[n0 + tn * 2], b1 = bias[n0 + tn * 2 + 1];
#pragma unroll
  for (int i = 0; i < 2; ++i) {
    float v0 = acc[i][0] + b0, v1 = acc[i][1] + b1;
    if (DO_TANH) { v0 = tanhf(v0); v1 = tanhf(v1); }
    float* dst = Cout + (size_t)(m0 + tm * 2 + i) * N + n0 + tn * 2;
    dst[0] = v0; dst[1] = v1;
  }
}

// cos GEMM via bf16-split MFMA. BM=128(all batch) x BN=64, BK=32, 256 thr, dbuf LDS.
__global__ __launch_bounds__(256, 2) void cos_gemm_mfma(
    const unsigned short* __restrict__ qh, const unsigned short* __restrict__ ql,
    const float* __restrict__ FQ, float* __restrict__ C) {
  __shared__ unsigned short Ah[2][128 * 32];
  __shared__ unsigned short Al[2][128 * 32];
  __shared__ unsigned short Bh[2][64 * 32];
  __shared__ unsigned short Bl[2][64 * 32];
  const int tid = threadIdx.x;
  const int lane = tid & 63, wid = tid >> 6;
  const int q0 = blockIdx.x * 64;

  int aldsb[2], asrc[2];
#pragma unroll
  for (int j = 0; j < 2; ++j) {
    const int row = wid * 32 + j * 16 + (lane >> 2);
    const int kg = (lane & 3) ^ ((row >> 1) & 3);
    aldsb[j] = (wid * 32 + j * 16) * 32;
    asrc[j] = row * HH + kg * 8;
  }
  const int br0 = tid >> 3, bc4 = tid & 7;
  const size_t bsrc0 = (size_t)(q0 + br0) * HH + bc4 * 4;
  const size_t bsrc1 = bsrc0 + (size_t)32 * HH;
  const int bkb = bc4 >> 1, bhalf = (bc4 & 1) * 4;
  const int bdst0 = br0 * 32 + ((bkb ^ ((br0 >> 1) & 3)) << 3) + bhalf;
  const int br1 = br0 + 32;
  const int bdst1 = br1 * 32 + ((bkb ^ ((br1 >> 1) & 3)) << 3) + bhalf;

  const int wm = wid >> 1, wn = wid & 1;
  int aoff[4], boff[2];
#pragma unroll
  for (int m = 0; m < 4; ++m) {
    const int row = wm * 64 + m * 16 + (lane & 15);
    const int kb = (lane >> 4) ^ ((row >> 1) & 3);
    aoff[m] = row * 32 + kb * 8;
  }
#pragma unroll
  for (int n = 0; n < 2; ++n) {
    const int col = wn * 32 + n * 16 + (lane & 15);
    const int kb = (lane >> 4) ^ ((col >> 1) & 3);
    boff[n] = col * 32 + kb * 8;
  }

  f32x4 acc[4][2];
#pragma unroll
  for (int m = 0; m < 4; ++m)
#pragma unroll
    for (int n = 0; n < 2; ++n) acc[m][n] = (f32x4){0.f, 0.f, 0.f, 0.f};

  {
    const float4 s0 = *reinterpret_cast<const float4*>(FQ + bsrc0);
    const float4 s1 = *reinterpret_cast<const float4*>(FQ + bsrc1);
#pragma unroll
    for (int j = 0; j < 2; ++j) {
      gl16(qh + asrc[j], &Ah[0][aldsb[j]]);
      gl16(ql + asrc[j], &Al[0][aldsb[j]]);
    }
    cvt4(s0, &Bh[0][bdst0], &Bl[0][bdst0]);
    cvt4(s1, &Bh[0][bdst1], &Bl[0][bdst1]);
    __syncthreads();
  }

  for (int t = 0; t < 24; ++t) {
    const int cb = t & 1, nb = cb ^ 1;
    float4 s0, s1;
    if (t < 23) {
      const int k0 = (t + 1) * 32;
      s0 = *reinterpret_cast<const float4*>(FQ + bsrc0 + k0);
      s1 = *reinterpret_cast<const float4*>(FQ + bsrc1 + k0);
#pragma unroll
      for (int j = 0; j < 2; ++j) {
        gl16(qh + k0 + asrc[j], &Ah[nb][aldsb[j]]);
        gl16(ql + k0 + asrc[j], &Al[nb][aldsb[j]]);
      }
    }
    short8 ah[4], al[4], bh[2], bl[2];
#pragma unroll
    for (int m = 0; m < 4; ++m) {
      ah[m] = *reinterpret_cast<const short8*>(&Ah[cb][aoff[m]]);
      al[m] = *reinterpret_cast<const short8*>(&Al[cb][aoff[m]]);
    }
#pragma unroll
    for (int n = 0; n < 2; ++n) {
      bh[n] = *reinterpret_cast<const short8*>(&Bh[cb][boff[n]]);
      bl[n] = *reinterpret_cast<const short8*>(&Bl[cb][boff[n]]);
    }
#pragma unroll
    for (int m = 0; m < 4; ++m)
#pragma unroll
      for (int n = 0; n < 2; ++n) {
        acc[m][n] = __builtin_amdgcn_mfma_f32_16x16x32_bf16(ah[m], bh[n], acc[m][n], 0, 0, 0);
        acc[m][n] = __builtin_amdgcn_mfma_f32_16x16x32_bf16(al[m], bh[n], acc[m][n], 0, 0, 0);
        acc[m][n] = __builtin_amdgcn_mfma_f32_16x16x32_bf16(ah[m], bl[n], acc[m][n], 0, 0, 0);
      }
    if (t < 23) {
      cvt4(s0, &Bh[nb][bdst0], &Bl[nb][bdst0]);
      cvt4(s1, &Bh[nb][bdst1], &Bl[nb][bdst1]);
    }
    __syncthreads();
  }

  const int crow = wm * 64 + (lane >> 4) * 4;
  const int ccol = q0 + wn * 32 + (lane & 15);
#pragma unroll
  for (int m = 0; m < 4; ++m)
#pragma unroll
    for (int n = 0; n < 2; ++n)
#pragma unroll
      for (int r = 0; r < 4; ++r)
        C[(size_t)(crow + m * 16 + r) * KQ + ccol + n * 16] = acc[m][n][r];
}

// L2-normalize rows of Y and emit bf16 hi/lo split.
__global__ __launch_bounds__(256) void l2norm_split(const float* __restrict__ Y,
                                                    unsigned short* __restrict__ qh,
                                                    unsigned short* __restrict__ ql) {
  const int b = blockIdx.x, tid = threadIdx.x;
  __shared__ float sh[4];
  __shared__ float snorm;
  float ss = 0.f;
  for (int h = tid; h < HH; h += 256) {
    const float v = Y[(size_t)b * HH + h];
    ss = fmaf(v, v, ss);
  }
  for (int o = 32; o; o >>= 1) ss += __shfl_down(ss, o);
  const int lane = tid & 63, wid = tid >> 6;
  if (lane == 0) sh[wid] = ss;
  __syncthreads();
  if (tid == 0) snorm = 1.0f / sqrtf(sh[0] + sh[1] + sh[2] + sh[3]);
  __syncthreads();
  const float rs = snorm;
  for (int h = tid; h < HH; h += 256) {
    const float q = Y[(size_t)b * HH + h] * rs;
    const unsigned short hi = f2bf(q);
    qh[(size_t)b * HH + h] = hi;
    ql[(size_t)b * HH + h] = f2bf(q - bf2f(hi));
  }
}

__global__ __launch_bounds__(256) void cls_loss_kernel(
    const float* __restrict__ H1, const float* __restrict__ W2,
    const float* __restrict__ b2, const int* __restrict__ labels,
    float* __restrict__ out) {
  const int b = blockIdx.x, tid = threadIdx.x;
  __shared__ float sh0[4], sh1[4];
  float p0 = 0.f, p1 = 0.f;
  for (int h = tid; h < HH; h += 256) {
    const float v = H1[(size_t)b * HH + h];
    p0 = fmaf(v, W2[h * 2 + 0], p0);
    p1 = fmaf(v, W2[h * 2 + 1], p1);
  }
  for (int o = 32; o; o >>= 1) {
    p0 += __shfl_down(p0, o);
    p1 += __shfl_down(p1, o);
  }
  const int lane = tid & 63, wid = tid >> 6;
  if (lane == 0) { sh0[wid] = p0; sh1[wid] = p1; }
  __syncthreads();
  if (tid == 0) {
    const float l0 = sh0[0] + sh0[1] + sh0[2] + sh0[3] + b2[0];
    const float l1 = sh1[0] + sh1[1] + sh1[2] + sh1[3] + b2[1];
    const float mx = fmaxf(l0, l1), mn = fminf(l0, l1);
    const float lse = mx + log1pf(__expf(mn - mx));
    const float ce = lse - (labels[b] ? l1 : l0);
    atomicAdd(out, 0.9f * ce * (1.0f / 128.0f));
  }
}

__global__ __launch_bounds__(1024) void counts_kernel(const int* __restrict__ labels,
                                                      const int* __restrict__ lq,
                                                      int* __restrict__ m_out,
                                                      unsigned* __restrict__ qmask) {
  const int tid = threadIdx.x;
  __shared__ int sh[16];
  __shared__ int has[2];
  unsigned mask = 0u;
  const int base = tid << 5;
#pragma unroll
  for (int j = 0; j < 32; ++j) mask |= (unsigned)(lq[base + j] != 0) << j;
  qmask[tid] = mask;
  int c = __popc(mask);
  for (int o = 32; o; o >>= 1) c += __shfl_down(c, o);
  const int lane = tid & 63, wid = tid >> 6;
  if (tid < 2) has[tid] = 0;
  __syncthreads();
  if (lane == 0) sh[wid] = c;
  if (tid < BB) has[labels[tid]] = 1;
  __syncthreads();
  if (tid == 0) {
    int n1 = 0;
    for (int w = 0; w < 16; ++w) n1 += sh[w];
    const int n0 = KQ - n1;
    int mm = 0x7fffffff;
    if (has[0] && n0 < mm) mm = n0;
    if (has[1] && n1 < mm) mm = n1;
    *m_out = mm;
  }
}

// Pass A (row read + neg-lse + pos key compaction + pos min/max), then
// histogram radix-select for ranks {25, m-25, m}, then one gather pass.
__global__ __launch_bounds__(1024) void select_kernel(
    const float* __restrict__ Cm, const int* __restrict__ labels,
    const unsigned* __restrict__ qmask, const int* __restrict__ m_ptr,
    float* __restrict__ out) {
  const int b = blockIdx.x;
  const int tid = threadIdx.x;
  const int lane = tid & 63, wid = tid >> 6;
  const float* __restrict__ row = Cm + (size_t)b * KQ;
  const int lab = labels[b];
  const int m = *m_ptr;

  __shared__ __align__(16) unsigned poskeys[PCAP];
  __shared__ unsigned hist[NB + 1];
  __shared__ unsigned cand[3][CCAP];
  __shared__ int candn[3];
  __shared__ float redm[16], reds[16], redmin[16], redmax[16];
  __shared__ unsigned wsum[16];
  __shared__ int abin[3], acnt[3];
  __shared__ unsigned akey[3];
  __shared__ unsigned long long accg;
  __shared__ float gs0, gsm, s_logE, s_vmin, s_vmax;
  __shared__ int s_cnt;

  if (tid == 0) { s_cnt = 0; gs0 = 0.f; gsm = 0.f; accg = 0ull; }
  if (tid < 3) candn[tid] = 0;
  __syncthreads();

  // ---------- Pass A ----------
  const unsigned qm = qmask[tid];
  const unsigned pmask = lab ? qm : ~qm;
  const int base = tid << 5;
  float va[32];
#pragma unroll
  for (int u = 0; u < 8; ++u) {
    const float4 v = *reinterpret_cast<const float4*>(row + base + (u << 2));
    va[(u << 2) + 0] = v.x; va[(u << 2) + 1] = v.y;
    va[(u << 2) + 2] = v.z; va[(u << 2) + 3] = v.w;
  }
  float mneg = -3.0e38f, sneg = 0.f, vmin = 3.0e38f, vmax = -3.0e38f;
#pragma unroll
  for (int j = 0; j < 32; ++j) {
    if ((pmask >> j) & 1u) {
      vmin = fminf(vmin, va[j]);
      vmax = fmaxf(vmax, va[j]);
    } else {
      mneg = fmaxf(mneg, va[j] * TINV);
    }
  }
#pragma unroll
  for (int j = 0; j < 32; ++j) {
    if (!((pmask >> j) & 1u)) sneg += __expf(va[j] * TINV - mneg);
  }
#pragma unroll
  for (int o = 32; o; o >>= 1) {
    const float mo = __shfl_down(mneg, o), so = __shfl_down(sneg, o);
    const float M = fmaxf(mneg, mo);
    sneg = sneg * __expf(mneg - M) + so * __expf(mo - M);
    mneg = M;
    vmin = fminf(vmin, __shfl_down(vmin, o));
    vmax = fmaxf(vmax, __shfl_down(vmax, o));
  }
  if (lane == 0) { redm[wid] = mneg; reds[wid] = sneg; redmin[wid] = vmin; redmax[wid] = vmax; }

  // compact positive keys
  const int np = __popc(pmask);
  unsigned incl = (unsigned)np;
#pragma unroll
  for (int o = 1; o < 64; o <<= 1) {
    const unsigned t = __shfl_up(incl, o);
    if (lane >= o) incl += t;
  }
  const unsigned excl = incl - (unsigned)np;
  const unsigned wtot = __shfl(incl, 63);
  unsigned wbase = 0u;
  if (lane == 63) wbase = (unsigned)atomicAdd(&s_cnt, (int)wtot);
  wbase = __shfl(wbase, 63);
  const int ofs = (int)(wbase + excl);
  if (ofs + np <= PCAP) {
#pragma unroll
    for (int j = 0; j < 32; ++j) {
      if ((pmask >> j) & 1u)
        poskeys[ofs + __popc(pmask & ((1u << j) - 1u))] = f2key(va[j]);
    }
  }
  __syncthreads();

  const int P = s_cnt;
  if (tid == 0) {
    float M = redm[0], S = 0.f;
    float mn = redmin[0], mx = redmax[0];
    for (int w = 1; w < 16; ++w) {
      M = fmaxf(M, redm[w]);
      mn = fminf(mn, redmin[w]);
      mx = fmaxf(mx, redmax[w]);
    }
    for (int w = 0; w < 16; ++w) S += reds[w] * __expf(redm[w] - M);
    s_logE = M + logf(S);
    s_vmin = mn;
    s_vmax = mx;
  }
  if (tid < ((4 - (P & 3)) & 3)) poskeys[P + tid] = 0u;  // pad for uint4 gather
  for (int i = tid; i < NB + 1; i += 1024) hist[i] = 0u;
  __syncthreads();

  const float cE = s_logE;
  const float vmn = s_vmin;
  const float scale = (float)NB * (1.0f - 1e-6f) / fmaxf(s_vmax - vmn, 1e-30f);
  auto key2bin = [&](unsigned k) {
    int bn = (int)((key2f(k) - vmn) * scale);
    return bn < 0 ? 0 : (bn > NB - 1 ? NB - 1 : bn);
  };

  // ---------- histogram ----------
  for (int i = tid; i < P; i += 1024) atomicAdd(&hist[key2bin(poskeys[i])], 1u);
  __syncthreads();

  // ---------- block exclusive prefix scan over NB bins (4 per thread) ----------
  const int t4 = tid << 2;
  const unsigned h0 = hist[t4], h1 = hist[t4 + 1], h2 = hist[t4 + 2], h3 = hist[t4 + 3];
  const unsigned part = h0 + h1 + h2 + h3;
  unsigned sinc = part;
#pragma unroll
  for (int o = 1; o < 64; o <<= 1) {
    const unsigned t = __shfl_up(sinc, o);
    if (lane >= o) sinc += t;
  }
  if (lane == 63) wsum[wid] = sinc;
  __syncthreads();
  unsigned woff = 0;
  for (int w = 0; w < wid; ++w) woff += wsum[w];
  const unsigned exb = woff + sinc - part;
  hist[t4] = exb; hist[t4 + 1] = exb + h0; hist[t4 + 2] = exb + h0 + h1;
  hist[t4 + 3] = exb + h0 + h1 + h2;
  if (tid == 1023) hist[NB] = exb + part;  // == P
  __syncthreads();

  // ---------- locate target bins ----------
  const int rt0 = 25, rt1 = m - 25, rt2 = m;  // descending 1-based ranks
  const unsigned idx0 = (unsigned)(P - rt0), idx1 = (unsigned)(P - rt1), idx2 = (unsigned)(P - rt2);
#pragma unroll
  for (int i = 0; i < 4; ++i) {
    const int bb = t4 + i;
    const unsigned pb = hist[bb], pb1 = hist[bb + 1];
    if (pb <= idx0 && idx0 < pb1) { abin[0] = bb; acnt[0] = P - (int)pb1; }
    if (pb <= idx1 && idx1 < pb1) { abin[1] = bb; acnt[1] = P - (int)pb1; }
    if (pb <= idx2 && idx2 < pb1) { abin[2] = bb; acnt[2] = P - (int)pb1; }
  }
  __syncthreads();

  // ---------- collect candidates in target bins ----------
  const int tb0 = abin[0], tb1 = abin[1], tb2 = abin[2];
  for (int i = tid; i < P; i += 1024) {
    const unsigned k = poskeys[i];
    const int bn = key2bin(k);
    if (bn == tb0) { const int p = atomicAdd(&candn[0], 1); if (p < CCAP) cand[0][p] = k; }
    if (bn == tb1) { const int p = atomicAdd(&candn[1], 1); if (p < CCAP) cand[1][p] = k; }
    if (bn == tb2) { const int p = atomicAdd(&candn[2], 1); if (p < CCAP) cand[2][p] = k; }
  }
  __syncthreads();

  // ---------- exact rank-within-bin selection: one wave per target ----------
  if (wid < 3) {
    const int j = wid;
    const int rts[3] = {rt0, rt1, rt2};
    const int cnt = candn[j] < CCAP ? candn[j] : CCAP;
    const int rr = rts[j] - acnt[j];  // 1-based descending rank within candidates
    for (int i = lane; i < cnt; i += 64) {
      const unsigned k = cand[j][i];
      int gt = 0, eq = 0;
      for (int q = 0; q < cnt; ++q) {
        const unsigned kq = cand[j][q];
        gt += (kq > k);
        eq += (kq == k);
      }
      if (gt < rr && rr <= gt + eq) akey[j] = k;
    }
  }
  __syncthreads();

  const unsigned a0 = akey[0], a1 = akey[1], a2 = akey[2];
  const int P4c = (P + 3) >> 2;
  const uint4* __restrict__ pk4 = reinterpret_cast<const uint4*>(poskeys);

  // ---------- gather ----------
  float s0 = 0.f, sm = 0.f;
  unsigned q0c = 0, q1c = 0, q2c = 0;
  for (int i = tid; i < P4c; i += 1024) {
    const uint4 kv = pk4[i];
    const unsigned ks[4] = {kv.x, kv.y, kv.z, kv.w};
#pragma unroll
    for (int j = 0; j < 4; ++j) {
      const unsigned k = ks[j];
      if (k > a2) {
        ++q2c;
        const bool top = (k > a0), mid = (k <= a1);
        if (k > a1) ++q1c;
        if (top) ++q0c;
        if (top || mid) {
          const float a = key2f(k) * TINV;
          const float d = cE - a;
          const float fv = fmaxf(d, 0.f) + log1pf(__expf(-fabsf(d)));
          if (top) s0 += fv;
          if (mid) sm += fv;
        }
      }
    }
  }
  unsigned long long pc = (unsigned long long)q0c |
                          ((unsigned long long)q1c << 20) |
                          ((unsigned long long)q2c << 40);
#pragma unroll
  for (int o = 32; o; o >>= 1) {
    s0 += __shfl_down(s0, o);
    sm += __shfl_down(sm, o);
    pc += shfl_down_u64(pc, o);
  }
  if (lane == 0) {
    atomicAdd(&gs0, s0);
    atomicAdd(&gsm, sm);
    atomicAdd(&accg, pc);
  }
  __syncthreads();
  if (tid == 0) {
    const unsigned long long t = accg;
    const float C0 = (float)(unsigned)(t & 0xFFFFFu);
    const float C1 = (float)(unsigned)((t >> 20) & 0xFFFFFu);
    const float C2 = (float)(unsigned)((t >> 40) & 0xFFFFFu);
    auto fval = [&](unsigned kk) {
      const float a = key2f(kk) * TINV;
      const float d = cE - a;
      return fmaxf(d, 0.f) + log1pf(__expf(-fabsf(d)));
    };
    const float f0 = fval(a0), f1 = fval(a1), f2 = fval(a2);
    const float top25 = gs0 + (25.0f - C0) * f0;
    const float mid = gsm + ((float)m - C2) * f2 - ((float)(m - 25) - C1) * f1;
    atomicAdd(out, 0.1f * (top25 + mid) * (1.0f / 6400.0f));
  }
}

extern "C" void kernel_launch(void* const* d_in, const int* in_sizes, int n_in,
                              void* d_out, int out_size, void* d_ws, size_t ws_size,
                              hipStream_t stream) {
  const float* pooled = (const float*)d_in[0];
  const int* labels = (const int*)d_in[1];
  const float* fq = (const float*)d_in[2];
  const int* lq = (const int*)d_in[3];
  const float* cls_dw = (const float*)d_in[4];
  const float* cls_db = (const float*)d_in[5];
  const float* cls_ow = (const float*)d_in[6];
  const float* cls_ob = (const float*)d_in[7];
  const float* con_dw = (const float*)d_in[8];
  const float* con_db = (const float*)d_in[9];
  const float* con_ow = (const float*)d_in[10];
  const float* con_ob = (const float*)d_in[11];
  float* out = (float*)d_out;

  float* ws = (float*)d_ws;
  float* H1 = ws;                                        // 128*768 f32
  float* H2 = ws + 98304;                                // 128*768 f32
  float* Y = ws + 2 * 98304;                             // 128*768 f32
  unsigned short* qh = (unsigned short*)(ws + 3 * 98304);          // 128*768 bf16
  unsigned short* ql = (unsigned short*)(ws + 3 * 98304 + 49152);  // 128*768 bf16
  float* C = ws + 4 * 98304;                             // 128*32768 f32
  int* mptr = (int*)(ws + 4 * 98304 + (size_t)BB * KQ);
  unsigned* qmask = (unsigned*)(mptr + 1);               // 1024 words

  zero_out<<<1, 1, 0, stream>>>(out);
  gemm_bias_act32<true><<<dim3(24, 4), 256, 0, stream>>>(pooled, cls_dw, cls_db, H1, HH, HH);
  gemm_bias_act32<true><<<dim3(24, 4), 256, 0, stream>>>(pooled, con_dw, con_db, H2, HH, HH);
  gemm_bias_act32<false><<<dim3(24, 4), 256, 0, stream>>>(H2, con_ow, con_ob, Y, HH, HH);
  l2norm_split<<<128, 256, 0, stream>>>(Y, qh, ql);
  cls_loss_kernel<<<128, 256, 0, stream>>>(H1, cls_ow, cls_ob, labels, out);
  counts_kernel<<<1, 1024, 0, stream>>>(labels, lq, mptr, qmask);
  cos_gemm_mfma<<<KQ / 64, 256, 0, stream>>>(qh, ql, fq, C);
  select_kernel<<<128, 1024, 0, stream>>>(C, labels, qmask, mptr, out);
}

// Round 5
// 125.128 us; speedup vs baseline: 3.7375x; 1.2586x over previous
//
#include <hip/hip_runtime.h>
#include <math.h>

#define BB 128
#define HH 768
#define KQ 32768
#define PCAP 18432  // max positives per row staged in LDS
#define NB 4096     // histogram bins
#define CCAP 512    // candidate cap per target bin

constexpr float TINV = 1.0f / 0.07f;

typedef __attribute__((ext_vector_type(8))) short short8;
typedef __attribute__((ext_vector_type(4))) float f32x4;
typedef __attribute__((address_space(3))) void lds_void;
typedef const __attribute__((address_space(1))) void gbl_void;

__device__ __forceinline__ unsigned short f2bf(float f) {
  unsigned u = __float_as_uint(f);
  unsigned r = u + 0x7FFFu + ((u >> 16) & 1u);  // RNE
  return (unsigned short)(r >> 16);
}
__device__ __forceinline__ float bf2f(unsigned short h) {
  return __uint_as_float(((unsigned)h) << 16);
}
__device__ __forceinline__ unsigned f2key(float f) {
  unsigned u = __float_as_uint(f);
  return u ^ (unsigned)(((int)u >> 31) | 0x80000000);
}
__device__ __forceinline__ float key2f(unsigned k) {
  unsigned u = (k & 0x80000000u) ? (k & 0x7FFFFFFFu) : ~k;
  return __uint_as_float(u);
}
__device__ __forceinline__ unsigned long long shfl_down_u64(unsigned long long v, int o) {
  unsigned lo = (unsigned)v, hi = (unsigned)(v >> 32);
  lo = __shfl_down(lo, o);
  hi = __shfl_down(hi, o);
  return ((unsigned long long)hi << 32) | lo;
}
__device__ __forceinline__ void gl16(const unsigned short* g, unsigned short* l) {
  __builtin_amdgcn_global_load_lds((gbl_void*)g, (lds_void*)l, 16, 0, 0);
}
__device__ __forceinline__ void cvt4(const float4 v, unsigned short* ph, unsigned short* pl) {
  const unsigned short h0 = f2bf(v.x), h1 = f2bf(v.y), h2 = f2bf(v.z), h3 = f2bf(v.w);
  const unsigned short l0 = f2bf(v.x - bf2f(h0)), l1 = f2bf(v.y - bf2f(h1));
  const unsigned short l2 = f2bf(v.z - bf2f(h2)), l3 = f2bf(v.w - bf2f(h3));
  *reinterpret_cast<ushort4*>(ph) = make_ushort4(h0, h1, h2, h3);
  *reinterpret_cast<ushort4*>(pl) = make_ushort4(l0, l1, l2, l3);
}

// C = tanh(A @ W{0,1} + b{0,1}); z picks head. BM=BN=32, BK=32, 256 thr.
__global__ __launch_bounds__(256) void dense_pair(
    const float* __restrict__ A, const float* __restrict__ W0,
    const float* __restrict__ b0, float* __restrict__ C0,
    const float* __restrict__ W1, const float* __restrict__ b1,
    float* __restrict__ C1) {
  const float* W = blockIdx.z ? W1 : W0;
  const float* bias = blockIdx.z ? b1 : b0;
  float* Cout = blockIdx.z ? C1 : C0;
  __shared__ float As[32][33];
  __shared__ float Ws[32][36];
  const int n0 = blockIdx.x * 32;
  const int m0 = blockIdx.y * 32;
  const int tid = threadIdx.x;
  const int tn = tid & 15, tm = tid >> 4;
  const int r = tid >> 3, c = (tid & 7) << 2;
  float acc[2][2] = {};
  for (int k0 = 0; k0 < HH; k0 += 32) {
    const float4 a4 = *reinterpret_cast<const float4*>(A + (size_t)(m0 + r) * HH + k0 + c);
    As[c + 0][r] = a4.x; As[c + 1][r] = a4.y; As[c + 2][r] = a4.z; As[c + 3][r] = a4.w;
    const float4 w4 = *reinterpret_cast<const float4*>(W + (size_t)(k0 + r) * HH + n0 + c);
    *reinterpret_cast<float4*>(&Ws[r][c]) = w4;
    __syncthreads();
#pragma unroll
    for (int kk = 0; kk < 32; ++kk) {
      const float a0 = As[kk][tm * 2], a1 = As[kk][tm * 2 + 1];
      const float w0 = Ws[kk][tn * 2], w1 = Ws[kk][tn * 2 + 1];
      acc[0][0] = fmaf(a0, w0, acc[0][0]); acc[0][1] = fmaf(a0, w1, acc[0][1]);
      acc[1][0] = fmaf(a1, w0, acc[1][0]); acc[1][1] = fmaf(a1, w1, acc[1][1]);
    }
    __syncthreads();
  }
  const float b0v = bias[n0 + tn * 2], b1v = bias[n0 + tn * 2 + 1];
#pragma unroll
  for (int i = 0; i < 2; ++i) {
    float* dst = Cout + (size_t)(m0 + tm * 2 + i) * HH + n0 + tn * 2;
    dst[0] = tanhf(acc[i][0] + b0v);
    dst[1] = tanhf(acc[i][1] + b1v);
  }
}

// C = A @ W + b (no act). BM=BN=32, BK=32.
__global__ __launch_bounds__(256) void gemm_bias(
    const float* __restrict__ A, const float* __restrict__ W,
    const float* __restrict__ bias, float* __restrict__ Cout) {
  __shared__ float As[32][33];
  __shared__ float Ws[32][36];
  const int n0 = blockIdx.x * 32;
  const int m0 = blockIdx.y * 32;
  const int tid = threadIdx.x;
  const int tn = tid & 15, tm = tid >> 4;
  const int r = tid >> 3, c = (tid & 7) << 2;
  float acc[2][2] = {};
  for (int k0 = 0; k0 < HH; k0 += 32) {
    const float4 a4 = *reinterpret_cast<const float4*>(A + (size_t)(m0 + r) * HH + k0 + c);
    As[c + 0][r] = a4.x; As[c + 1][r] = a4.y; As[c + 2][r] = a4.z; As[c + 3][r] = a4.w;
    const float4 w4 = *reinterpret_cast<const float4*>(W + (size_t)(k0 + r) * HH + n0 + c);
    *reinterpret_cast<float4*>(&Ws[r][c]) = w4;
    __syncthreads();
#pragma unroll
    for (int kk = 0; kk < 32; ++kk) {
      const float a0 = As[kk][tm * 2], a1 = As[kk][tm * 2 + 1];
      const float w0 = Ws[kk][tn * 2], w1 = Ws[kk][tn * 2 + 1];
      acc[0][0] = fmaf(a0, w0, acc[0][0]); acc[0][1] = fmaf(a0, w1, acc[0][1]);
      acc[1][0] = fmaf(a1, w0, acc[1][0]); acc[1][1] = fmaf(a1, w1, acc[1][1]);
    }
    __syncthreads();
  }
  const float b0v = bias[n0 + tn * 2], b1v = bias[n0 + tn * 2 + 1];
#pragma unroll
  for (int i = 0; i < 2; ++i) {
    float* dst = Cout + (size_t)(m0 + tm * 2 + i) * HH + n0 + tn * 2;
    dst[0] = acc[i][0] + b0v;
    dst[1] = acc[i][1] + b1v;
  }
}

// cos GEMM via bf16-split MFMA. BM=64 x BN=64, BK=32, 256 thr, dbuf LDS,
// 1024 blocks (4/CU, 16 waves/CU), XCD-swizzled so mhalf pairs share an XCD.
__global__ __launch_bounds__(256, 4) void cos_gemm_mfma(
    const unsigned short* __restrict__ qh, const unsigned short* __restrict__ ql,
    const float* __restrict__ FQ, float* __restrict__ C) {
  __shared__ unsigned short Ah[2][64 * 32];
  __shared__ unsigned short Al[2][64 * 32];
  __shared__ unsigned short Bh[2][64 * 32];
  __shared__ unsigned short Bl[2][64 * 32];
  const int tid = threadIdx.x;
  const int lane = tid & 63, wid = tid >> 6;
  // bijective XCD swizzle (nwg=1024, 1024%8==0): contiguous logical chunk per XCD
  const int bid = blockIdx.x;
  const int swz = (bid & 7) * 128 + (bid >> 3);
  const int q0 = (swz >> 1) * 64;
  const int mb = (swz & 1) * 64;

  // A staging: wave wid stages rows [wid*16, wid*16+16); pre-swizzled global src.
  const int arow = wid * 16 + (lane >> 2);
  const int akg = (lane & 3) ^ ((arow >> 1) & 3);
  const int aldsb = wid * 16 * 32;                 // uniform ushort base per wave
  const int asrc = (mb + arow) * HH + akg * 8;     // per-lane global ushort offset
  // B staging: thread covers rows br0 and br0+32, 4 floats at bc4*4.
  const int br0 = tid >> 3, bc4 = tid & 7;
  const size_t bsrc0 = (size_t)(q0 + br0) * HH + bc4 * 4;
  const size_t bsrc1 = bsrc0 + (size_t)32 * HH;
  const int bkb = bc4 >> 1, bhalf = (bc4 & 1) * 4;
  const int bdst0 = br0 * 32 + ((bkb ^ ((br0 >> 1) & 3)) << 3) + bhalf;
  const int br1 = br0 + 32;
  const int bdst1 = br1 * 32 + ((bkb ^ ((br1 >> 1) & 3)) << 3) + bhalf;

  // compute-side fragment offsets (swizzled); wave (wm,wn) covers 32x32
  const int wm = wid >> 1, wn = wid & 1;
  int aoff[2], boff[2];
#pragma unroll
  for (int m = 0; m < 2; ++m) {
    const int row = wm * 32 + m * 16 + (lane & 15);
    const int kb = (lane >> 4) ^ ((row >> 1) & 3);
    aoff[m] = row * 32 + kb * 8;
  }
#pragma unroll
  for (int n = 0; n < 2; ++n) {
    const int col = wn * 32 + n * 16 + (lane & 15);
    const int kb = (lane >> 4) ^ ((col >> 1) & 3);
    boff[n] = col * 32 + kb * 8;
  }

  f32x4 acc[2][2];
#pragma unroll
  for (int m = 0; m < 2; ++m)
#pragma unroll
    for (int n = 0; n < 2; ++n) acc[m][n] = (f32x4){0.f, 0.f, 0.f, 0.f};

  {
    const float4 s0 = *reinterpret_cast<const float4*>(FQ + bsrc0);
    const float4 s1 = *reinterpret_cast<const float4*>(FQ + bsrc1);
    gl16(qh + asrc, &Ah[0][aldsb]);
    gl16(ql + asrc, &Al[0][aldsb]);
    cvt4(s0, &Bh[0][bdst0], &Bl[0][bdst0]);
    cvt4(s1, &Bh[0][bdst1], &Bl[0][bdst1]);
    __syncthreads();
  }

  for (int t = 0; t < 24; ++t) {
    const int cb = t & 1, nb = cb ^ 1;
    float4 s0, s1;
    if (t < 23) {
      const int k0 = (t + 1) * 32;
      s0 = *reinterpret_cast<const float4*>(FQ + bsrc0 + k0);
      s1 = *reinterpret_cast<const float4*>(FQ + bsrc1 + k0);
      gl16(qh + k0 + asrc, &Ah[nb][aldsb]);
      gl16(ql + k0 + asrc, &Al[nb][aldsb]);
    }
    short8 ah[2], al[2], bh[2], bl[2];
#pragma unroll
    for (int m = 0; m < 2; ++m) {
      ah[m] = *reinterpret_cast<const short8*>(&Ah[cb][aoff[m]]);
      al[m] = *reinterpret_cast<const short8*>(&Al[cb][aoff[m]]);
    }
#pragma unroll
    for (int n = 0; n < 2; ++n) {
      bh[n] = *reinterpret_cast<const short8*>(&Bh[cb][boff[n]]);
      bl[n] = *reinterpret_cast<const short8*>(&Bl[cb][boff[n]]);
    }
#pragma unroll
    for (int m = 0; m < 2; ++m)
#pragma unroll
      for (int n = 0; n < 2; ++n) {
        acc[m][n] = __builtin_amdgcn_mfma_f32_16x16x32_bf16(ah[m], bh[n], acc[m][n], 0, 0, 0);
        acc[m][n] = __builtin_amdgcn_mfma_f32_16x16x32_bf16(al[m], bh[n], acc[m][n], 0, 0, 0);
        acc[m][n] = __builtin_amdgcn_mfma_f32_16x16x32_bf16(ah[m], bl[n], acc[m][n], 0, 0, 0);
      }
    if (t < 23) {
      cvt4(s0, &Bh[nb][bdst0], &Bl[nb][bdst0]);
      cvt4(s1, &Bh[nb][bdst1], &Bl[nb][bdst1]);
    }
    __syncthreads();
  }

  const int crow = mb + wm * 32 + (lane >> 4) * 4;
  const int ccol = q0 + wn * 32 + (lane & 15);
#pragma unroll
  for (int m = 0; m < 2; ++m)
#pragma unroll
    for (int n = 0; n < 2; ++n)
#pragma unroll
      for (int r = 0; r < 4; ++r)
        C[(size_t)(crow + m * 16 + r) * KQ + ccol + n * 16] = acc[m][n][r];
}

// L2-normalize rows of Y and emit bf16 hi/lo split.
__global__ __launch_bounds__(256) void l2norm_split(const float* __restrict__ Y,
                                                    unsigned short* __restrict__ qh,
                                                    unsigned short* __restrict__ ql) {
  const int b = blockIdx.x, tid = threadIdx.x;
  __shared__ float sh[4];
  __shared__ float snorm;
  float ss = 0.f;
  for (int h = tid; h < HH; h += 256) {
    const float v = Y[(size_t)b * HH + h];
    ss = fmaf(v, v, ss);
  }
  for (int o = 32; o; o >>= 1) ss += __shfl_down(ss, o);
  const int lane = tid & 63, wid = tid >> 6;
  if (lane == 0) sh[wid] = ss;
  __syncthreads();
  if (tid == 0) snorm = 1.0f / sqrtf(sh[0] + sh[1] + sh[2] + sh[3]);
  __syncthreads();
  const float rs = snorm;
  for (int h = tid; h < HH; h += 256) {
    const float q = Y[(size_t)b * HH + h] * rs;
    const unsigned short hi = f2bf(q);
    qh[(size_t)b * HH + h] = hi;
    ql[(size_t)b * HH + h] = f2bf(q - bf2f(hi));
  }
}

__global__ __launch_bounds__(256) void cls_loss_kernel(
    const float* __restrict__ H1, const float* __restrict__ W2,
    const float* __restrict__ b2, const int* __restrict__ labels,
    float* __restrict__ out) {
  const int b = blockIdx.x, tid = threadIdx.x;
  __shared__ float sh0[4], sh1[4];
  float p0 = 0.f, p1 = 0.f;
  for (int h = tid; h < HH; h += 256) {
    const float v = H1[(size_t)b * HH + h];
    p0 = fmaf(v, W2[h * 2 + 0], p0);
    p1 = fmaf(v, W2[h * 2 + 1], p1);
  }
  for (int o = 32; o; o >>= 1) {
    p0 += __shfl_down(p0, o);
    p1 += __shfl_down(p1, o);
  }
  const int lane = tid & 63, wid = tid >> 6;
  if (lane == 0) { sh0[wid] = p0; sh1[wid] = p1; }
  __syncthreads();
  if (tid == 0) {
    const float l0 = sh0[0] + sh0[1] + sh0[2] + sh0[3] + b2[0];
    const float l1 = sh1[0] + sh1[1] + sh1[2] + sh1[3] + b2[1];
    const float mx = fmaxf(l0, l1), mn = fminf(l0, l1);
    const float lse = mx + log1pf(__expf(mn - mx));
    const float ce = lse - (labels[b] ? l1 : l0);
    atomicAdd(out, 0.9f * ce * (1.0f / 128.0f));
  }
}

// Also zeroes out[0] and builds qmask (bit=1 iff label_queue[k]==1).
__global__ __launch_bounds__(1024) void counts_kernel(const int* __restrict__ labels,
                                                      const int* __restrict__ lq,
                                                      int* __restrict__ m_out,
                                                      unsigned* __restrict__ qmask,
                                                      float* __restrict__ out) {
  const int tid = threadIdx.x;
  __shared__ int sh[16];
  __shared__ int has[2];
  unsigned mask = 0u;
  const int base = tid << 5;
#pragma unroll
  for (int j = 0; j < 32; ++j) mask |= (unsigned)(lq[base + j] != 0) << j;
  qmask[tid] = mask;
  int c = __popc(mask);
  for (int o = 32; o; o >>= 1) c += __shfl_down(c, o);
  const int lane = tid & 63, wid = tid >> 6;
  if (tid < 2) has[tid] = 0;
  __syncthreads();
  if (lane == 0) sh[wid] = c;
  if (tid < BB) has[labels[tid]] = 1;
  __syncthreads();
  if (tid == 0) {
    int n1 = 0;
    for (int w = 0; w < 16; ++w) n1 += sh[w];
    const int n0 = KQ - n1;
    int mm = 0x7fffffff;
    if (has[0] && n0 < mm) mm = n0;
    if (has[1] && n1 < mm) mm = n1;
    *m_out = mm;
    out[0] = 0.0f;
  }
}

// Pass A (row read + neg-lse + pos key compaction + pos min/max), then
// histogram radix-select for ranks {25, m-25, m}, then one gather pass.
__global__ __launch_bounds__(1024) void select_kernel(
    const float* __restrict__ Cm, const int* __restrict__ labels,
    const unsigned* __restrict__ qmask, const int* __restrict__ m_ptr,
    float* __restrict__ out) {
  const int b = blockIdx.x;
  const int tid = threadIdx.x;
  const int lane = tid & 63, wid = tid >> 6;
  const float* __restrict__ row = Cm + (size_t)b * KQ;
  const int lab = labels[b];
  const int m = *m_ptr;

  __shared__ __align__(16) unsigned poskeys[PCAP];
  __shared__ unsigned hist[NB + 1];
  __shared__ unsigned cand[3][CCAP];
  __shared__ int candn[3];
  __shared__ float redm[16], reds[16], redmin[16], redmax[16];
  __shared__ unsigned wsum[16];
  __shared__ int abin[3], acnt[3];
  __shared__ unsigned akey[3];
  __shared__ unsigned long long accg;
  __shared__ float gs0, gsm, s_logE, s_vmin, s_vmax;
  __shared__ int s_cnt;

  if (tid == 0) { s_cnt = 0; gs0 = 0.f; gsm = 0.f; accg = 0ull; }
  if (tid < 3) candn[tid] = 0;
  __syncthreads();

  // ---------- Pass A ----------
  const unsigned qm = qmask[tid];
  const unsigned pmask = lab ? qm : ~qm;
  const int base = tid << 5;
  float va[32];
#pragma unroll
  for (int u = 0; u < 8; ++u) {
    const float4 v = *reinterpret_cast<const float4*>(row + base + (u << 2));
    va[(u << 2) + 0] = v.x; va[(u << 2) + 1] = v.y;
    va[(u << 2) + 2] = v.z; va[(u << 2) + 3] = v.w;
  }
  float mneg = -3.0e38f, sneg = 0.f, vmin = 3.0e38f, vmax = -3.0e38f;
#pragma unroll
  for (int j = 0; j < 32; ++j) {
    if ((pmask >> j) & 1u) {
      vmin = fminf(vmin, va[j]);
      vmax = fmaxf(vmax, va[j]);
    } else {
      mneg = fmaxf(mneg, va[j] * TINV);
    }
  }
#pragma unroll
  for (int j = 0; j < 32; ++j) {
    if (!((pmask >> j) & 1u)) sneg += __expf(va[j] * TINV - mneg);
  }
#pragma unroll
  for (int o = 32; o; o >>= 1) {
    const float mo = __shfl_down(mneg, o), so = __shfl_down(sneg, o);
    const float M = fmaxf(mneg, mo);
    sneg = sneg * __expf(mneg - M) + so * __expf(mo - M);
    mneg = M;
    vmin = fminf(vmin, __shfl_down(vmin, o));
    vmax = fmaxf(vmax, __shfl_down(vmax, o));
  }
  if (lane == 0) { redm[wid] = mneg; reds[wid] = sneg; redmin[wid] = vmin; redmax[wid] = vmax; }

  const int np = __popc(pmask);
  unsigned incl = (unsigned)np;
#pragma unroll
  for (int o = 1; o < 64; o <<= 1) {
    const unsigned t = __shfl_up(incl, o);
    if (lane >= o) incl += t;
  }
  const unsigned excl = incl - (unsigned)np;
  const unsigned wtot = __shfl(incl, 63);
  unsigned wbase = 0u;
  if (lane == 63) wbase = (unsigned)atomicAdd(&s_cnt, (int)wtot);
  wbase = __shfl(wbase, 63);
  const int ofs = (int)(wbase + excl);
  if (ofs + np <= PCAP) {
#pragma unroll
    for (int j = 0; j < 32; ++j) {
      if ((pmask >> j) & 1u)
        poskeys[ofs + __popc(pmask & ((1u << j) - 1u))] = f2key(va[j]);
    }
  }
  __syncthreads();

  const int P = s_cnt;
  if (tid == 0) {
    float M = redm[0], S = 0.f;
    float mn = redmin[0], mx = redmax[0];
    for (int w = 1; w < 16; ++w) {
      M = fmaxf(M, redm[w]);
      mn = fminf(mn, redmin[w]);
      mx = fmaxf(mx, redmax[w]);
    }
    for (int w = 0; w < 16; ++w) S += reds[w] * __expf(redm[w] - M);
    s_logE = M + logf(S);
    s_vmin = mn;
    s_vmax = mx;
  }
  if (tid < ((4 - (P & 3)) & 3)) poskeys[P + tid] = 0u;
  for (int i = tid; i < NB + 1; i += 1024) hist[i] = 0u;
  __syncthreads();

  const float cE = s_logE;
  const float vmn = s_vmin;
  const float scale = (float)NB * (1.0f - 1e-6f) / fmaxf(s_vmax - vmn, 1e-30f);
  auto key2bin = [&](unsigned k) {
    int bn = (int)((key2f(k) - vmn) * scale);
    return bn < 0 ? 0 : (bn > NB - 1 ? NB - 1 : bn);
  };

  for (int i = tid; i < P; i += 1024) atomicAdd(&hist[key2bin(poskeys[i])], 1u);
  __syncthreads();

  const int t4 = tid << 2;
  const unsigned h0 = hist[t4], h1 = hist[t4 + 1], h2 = hist[t4 + 2], h3 = hist[t4 + 3];
  const unsigned part = h0 + h1 + h2 + h3;
  unsigned sinc = part;
#pragma unroll
  for (int o = 1; o < 64; o <<= 1) {
    const unsigned t = __shfl_up(sinc, o);
    if (lane >= o) sinc += t;
  }
  if (lane == 63) wsum[wid] = sinc;
  __syncthreads();
  unsigned woff = 0;
  for (int w = 0; w < wid; ++w) woff += wsum[w];
  const unsigned exb = woff + sinc - part;
  hist[t4] = exb; hist[t4 + 1] = exb + h0; hist[t4 + 2] = exb + h0 + h1;
  hist[t4 + 3] = exb + h0 + h1 + h2;
  if (tid == 1023) hist[NB] = exb + part;
  __syncthreads();

  const int rt0 = 25, rt1 = m - 25, rt2 = m;
  const unsigned idx0 = (unsigned)(P - rt0), idx1 = (unsigned)(P - rt1), idx2 = (unsigned)(P - rt2);
#pragma unroll
  for (int i = 0; i < 4; ++i) {
    const int bb = t4 + i;
    const unsigned pb = hist[bb], pb1 = hist[bb + 1];
    if (pb <= idx0 && idx0 < pb1) { abin[0] = bb; acnt[0] = P - (int)pb1; }
    if (pb <= idx1 && idx1 < pb1) { abin[1] = bb; acnt[1] = P - (int)pb1; }
    if (pb <= idx2 && idx2 < pb1) { abin[2] = bb; acnt[2] = P - (int)pb1; }
  }
  __syncthreads();

  const int tb0 = abin[0], tb1 = abin[1], tb2 = abin[2];
  for (int i = tid; i < P; i += 1024) {
    const unsigned k = poskeys[i];
    const int bn = key2bin(k);
    if (bn == tb0) { const int p = atomicAdd(&candn[0], 1); if (p < CCAP) cand[0][p] = k; }
    if (bn == tb1) { const int p = atomicAdd(&candn[1], 1); if (p < CCAP) cand[1][p] = k; }
    if (bn == tb2) { const int p = atomicAdd(&candn[2], 1); if (p < CCAP) cand[2][p] = k; }
  }
  __syncthreads();

  if (wid < 3) {
    const int j = wid;
    const int rts[3] = {rt0, rt1, rt2};
    const int cnt = candn[j] < CCAP ? candn[j] : CCAP;
    const int rr = rts[j] - acnt[j];
    for (int i = lane; i < cnt; i += 64) {
      const unsigned k = cand[j][i];
      int gt = 0, eq = 0;
      for (int q = 0; q < cnt; ++q) {
        const unsigned kq = cand[j][q];
        gt += (kq > k);
        eq += (kq == k);
      }
      if (gt < rr && rr <= gt + eq) akey[j] = k;
    }
  }
  __syncthreads();

  const unsigned a0 = akey[0], a1 = akey[1], a2 = akey[2];
  const int P4c = (P + 3) >> 2;
  const uint4* __restrict__ pk4 = reinterpret_cast<const uint4*>(poskeys);

  float s0 = 0.f, sm = 0.f;
  unsigned q0c = 0, q1c = 0, q2c = 0;
  for (int i = tid; i < P4c; i += 1024) {
    const uint4 kv = pk4[i];
    const unsigned ks[4] = {kv.x, kv.y, kv.z, kv.w};
#pragma unroll
    for (int j = 0; j < 4; ++j) {
      const unsigned k = ks[j];
      if (k > a2) {
        ++q2c;
        const bool top = (k > a0), mid = (k <= a1);
        if (k > a1) ++q1c;
        if (top) ++q0c;
        if (top || mid) {
          const float a = key2f(k) * TINV;
          const float d = cE - a;
          const float fv = fmaxf(d, 0.f) + log1pf(__expf(-fabsf(d)));
          if (top) s0 += fv;
          if (mid) sm += fv;
        }
      }
    }
  }
  unsigned long long pc = (unsigned long long)q0c |
                          ((unsigned long long)q1c << 20) |
                          ((unsigned long long)q2c << 40);
#pragma unroll
  for (int o = 32; o; o >>= 1) {
    s0 += __shfl_down(s0, o);
    sm += __shfl_down(sm, o);
    pc += shfl_down_u64(pc, o);
  }
  if (lane == 0) {
    atomicAdd(&gs0, s0);
    atomicAdd(&gsm, sm);
    atomicAdd(&accg, pc);
  }
  __syncthreads();
  if (tid == 0) {
    const unsigned long long t = accg;
    const float C0 = (float)(unsigned)(t & 0xFFFFFu);
    const float C1 = (float)(unsigned)((t >> 20) & 0xFFFFFu);
    const float C2 = (float)(unsigned)((t >> 40) & 0xFFFFFu);
    auto fval = [&](unsigned kk) {
      const float a = key2f(kk) * TINV;
      const float d = cE - a;
      return fmaxf(d, 0.f) + log1pf(__expf(-fabsf(d)));
    };
    const float f0 = fval(a0), f1 = fval(a1), f2 = fval(a2);
    const float top25 = gs0 + (25.0f - C0) * f0;
    const float mid = gsm + ((float)m - C2) * f2 - ((float)(m - 25) - C1) * f1;
    atomicAdd(out, 0.1f * (top25 + mid) * (1.0f / 6400.0f));
  }
}

extern "C" void kernel_launch(void* const* d_in, const int* in_sizes, int n_in,
                              void* d_out, int out_size, void* d_ws, size_t ws_size,
                              hipStream_t stream) {
  const float* pooled = (const float*)d_in[0];
  const int* labels = (const int*)d_in[1];
  const float* fq = (const float*)d_in[2];
  const int* lq = (const int*)d_in[3];
  const float* cls_dw = (const float*)d_in[4];
  const float* cls_db = (const float*)d_in[5];
  const float* cls_ow = (const float*)d_in[6];
  const float* cls_ob = (const float*)d_in[7];
  const float* con_dw = (const float*)d_in[8];
  const float* con_db = (const float*)d_in[9];
  const float* con_ow = (const float*)d_in[10];
  const float* con_ob = (const float*)d_in[11];
  float* out = (float*)d_out;

  float* ws = (float*)d_ws;
  float* H1 = ws;                                        // 128*768 f32
  float* H2 = ws + 98304;                                // 128*768 f32
  float* Y = ws + 2 * 98304;                             // 128*768 f32
  unsigned short* qh = (unsigned short*)(ws + 3 * 98304);          // 128*768 bf16
  unsigned short* ql = (unsigned short*)(ws + 3 * 98304 + 49152);  // 128*768 bf16
  float* C = ws + 4 * 98304;                             // 128*32768 f32
  int* mptr = (int*)(ws + 4 * 98304 + (size_t)BB * KQ);
  unsigned* qmask = (unsigned*)(mptr + 1);               // 1024 words

  counts_kernel<<<1, 1024, 0, stream>>>(labels, lq, mptr, qmask, out);
  dense_pair<<<dim3(24, 4, 2), 256, 0, stream>>>(pooled, cls_dw, cls_db, H1,
                                                 con_dw, con_db, H2);
  gemm_bias<<<dim3(24, 4), 256, 0, stream>>>(H2, con_ow, con_ob, Y);
  l2norm_split<<<128, 256, 0, stream>>>(Y, qh, ql);
  cls_loss_kernel<<<128, 256, 0, stream>>>(H1, cls_ow, cls_ob, labels, out);
  cos_gemm_mfma<<<1024, 256, 0, stream>>>(qh, ql, fq, C);
  select_kernel<<<128, 1024, 0, stream>>>(C, labels, qmask, mptr, out);
}

// Round 6
// 112.617 us; speedup vs baseline: 4.1527x; 1.1111x over previous
//
#include <hip/hip_runtime.h>
#include <math.h>

#define BB 128
#define HH 768
#define KQ 32768
#define PCAP 18432  // max positives per row staged in LDS
#define NB 4096     // histogram bins
#define CCAP 512    // candidate cap per target bin

constexpr float TINV = 1.0f / 0.07f;

typedef __attribute__((ext_vector_type(8))) short short8;
typedef __attribute__((ext_vector_type(4))) float f32x4;
typedef __attribute__((address_space(3))) void lds_void;
typedef const __attribute__((address_space(1))) void gbl_void;

__device__ __forceinline__ unsigned short f2bf(float f) {
  unsigned u = __float_as_uint(f);
  unsigned r = u + 0x7FFFu + ((u >> 16) & 1u);  // RNE
  return (unsigned short)(r >> 16);
}
__device__ __forceinline__ float bf2f(unsigned short h) {
  return __uint_as_float(((unsigned)h) << 16);
}
__device__ __forceinline__ unsigned f2key(float f) {
  unsigned u = __float_as_uint(f);
  return u ^ (unsigned)(((int)u >> 31) | 0x80000000);
}
__device__ __forceinline__ float key2f(unsigned k) {
  unsigned u = (k & 0x80000000u) ? (k & 0x7FFFFFFFu) : ~k;
  return __uint_as_float(u);
}
__device__ __forceinline__ unsigned long long shfl_down_u64(unsigned long long v, int o) {
  unsigned lo = (unsigned)v, hi = (unsigned)(v >> 32);
  lo = __shfl_down(lo, o);
  hi = __shfl_down(hi, o);
  return ((unsigned long long)hi << 32) | lo;
}
__device__ __forceinline__ void gl16(const unsigned short* g, unsigned short* l) {
  __builtin_amdgcn_global_load_lds((gbl_void*)g, (lds_void*)l, 16, 0, 0);
}

// C = tanh(A @ W{0,1} + b{0,1}); z picks head. BM=BN=32, BK=32, 256 thr.
__global__ __launch_bounds__(256) void dense_pair(
    const float* __restrict__ A, const float* __restrict__ W0,
    const float* __restrict__ b0, float* __restrict__ C0,
    const float* __restrict__ W1, const float* __restrict__ b1,
    float* __restrict__ C1) {
  const float* W = blockIdx.z ? W1 : W0;
  const float* bias = blockIdx.z ? b1 : b0;
  float* Cout = blockIdx.z ? C1 : C0;
  __shared__ float As[32][33];
  __shared__ float Ws[32][36];
  const int n0 = blockIdx.x * 32;
  const int m0 = blockIdx.y * 32;
  const int tid = threadIdx.x;
  const int tn = tid & 15, tm = tid >> 4;
  const int r = tid >> 3, c = (tid & 7) << 2;
  float acc[2][2] = {};
  for (int k0 = 0; k0 < HH; k0 += 32) {
    const float4 a4 = *reinterpret_cast<const float4*>(A + (size_t)(m0 + r) * HH + k0 + c);
    As[c + 0][r] = a4.x; As[c + 1][r] = a4.y; As[c + 2][r] = a4.z; As[c + 3][r] = a4.w;
    const float4 w4 = *reinterpret_cast<const float4*>(W + (size_t)(k0 + r) * HH + n0 + c);
    *reinterpret_cast<float4*>(&Ws[r][c]) = w4;
    __syncthreads();
#pragma unroll
    for (int kk = 0; kk < 32; ++kk) {
      const float a0 = As[kk][tm * 2], a1 = As[kk][tm * 2 + 1];
      const float w0 = Ws[kk][tn * 2], w1 = Ws[kk][tn * 2 + 1];
      acc[0][0] = fmaf(a0, w0, acc[0][0]); acc[0][1] = fmaf(a0, w1, acc[0][1]);
      acc[1][0] = fmaf(a1, w0, acc[1][0]); acc[1][1] = fmaf(a1, w1, acc[1][1]);
    }
    __syncthreads();
  }
  const float b0v = bias[n0 + tn * 2], b1v = bias[n0 + tn * 2 + 1];
#pragma unroll
  for (int i = 0; i < 2; ++i) {
    float* dst = Cout + (size_t)(m0 + tm * 2 + i) * HH + n0 + tn * 2;
    dst[0] = tanhf(acc[i][0] + b0v);
    dst[1] = tanhf(acc[i][1] + b1v);
  }
}

// C = A @ W + b (no act). BM=BN=32, BK=32.
__global__ __launch_bounds__(256) void gemm_bias(
    const float* __restrict__ A, const float* __restrict__ W,
    const float* __restrict__ bias, float* __restrict__ Cout) {
  __shared__ float As[32][33];
  __shared__ float Ws[32][36];
  const int n0 = blockIdx.x * 32;
  const int m0 = blockIdx.y * 32;
  const int tid = threadIdx.x;
  const int tn = tid & 15, tm = tid >> 4;
  const int r = tid >> 3, c = (tid & 7) << 2;
  float acc[2][2] = {};
  for (int k0 = 0; k0 < HH; k0 += 32) {
    const float4 a4 = *reinterpret_cast<const float4*>(A + (size_t)(m0 + r) * HH + k0 + c);
    As[c + 0][r] = a4.x; As[c + 1][r] = a4.y; As[c + 2][r] = a4.z; As[c + 3][r] = a4.w;
    const float4 w4 = *reinterpret_cast<const float4*>(W + (size_t)(k0 + r) * HH + n0 + c);
    *reinterpret_cast<float4*>(&Ws[r][c]) = w4;
    __syncthreads();
#pragma unroll
    for (int kk = 0; kk < 32; ++kk) {
      const float a0 = As[kk][tm * 2], a1 = As[kk][tm * 2 + 1];
      const float w0 = Ws[kk][tn * 2], w1 = Ws[kk][tn * 2 + 1];
      acc[0][0] = fmaf(a0, w0, acc[0][0]); acc[0][1] = fmaf(a0, w1, acc[0][1]);
      acc[1][0] = fmaf(a1, w0, acc[1][0]); acc[1][1] = fmaf(a1, w1, acc[1][1]);
    }
    __syncthreads();
  }
  const float b0v = bias[n0 + tn * 2], b1v = bias[n0 + tn * 2 + 1];
#pragma unroll
  for (int i = 0; i < 2; ++i) {
    float* dst = Cout + (size_t)(m0 + tm * 2 + i) * HH + n0 + tn * 2;
    dst[0] = acc[i][0] + b0v;
    dst[1] = acc[i][1] + b1v;
  }
}

// cos GEMM: pure-bf16 MFMA. BM=128(all batch) x BN=128, 8 waves, grid=256.
// B (fq) streams global->reg (no LDS, no barrier coupling), 3-deep prefetch.
// A (queries) in LDS, staged per 256-k chunk (2 barriers per chunk only).
__global__ __launch_bounds__(512, 2) void cos_gemm_mfma(
    const unsigned short* __restrict__ qh, const float* __restrict__ FQ,
    float* __restrict__ C) {
  __shared__ unsigned short Alds[128 * 256];  // 64 KB: [row][kb'(32) * 8], swizzled
  const int tid = threadIdx.x;
  const int lane = tid & 63, wid = tid >> 6;  // 8 waves
  const int q0 = blockIdx.x * 128;

  // staging: wave wid stages rows [wid*16, wid*16+16) via 8 gl16 (2 rows each).
  // lds slot kb' = lane&31 holds source kb = kb' ^ (row&7)  (bank-spread swizzle)
  int asrc[8];
#pragma unroll
  for (int j = 0; j < 8; ++j) {
    const int row = wid * 16 + j * 2 + (lane >> 5);
    const int kb = (lane & 31) ^ (row & 7);
    asrc[j] = row * HH + kb * 8;  // ushort offset (add kc per chunk)
  }
  // compute-side: A-frag row = m*16 + (lane&15); k-quarter = lane>>4.
  const int a_r = lane & 15;
  const int a_kq = lane >> 4;
  const int a_swz = a_r & 7;                 // row&7 (m*16 doesn't affect mod 8)
  const int a_rowbase = a_r * 256;           // ushort
  // B: col = fq row = q0 + wid*16 + (lane&15); 8 contiguous fp32 per lane.
  const float* __restrict__ bptr = FQ + (size_t)(q0 + wid * 16 + a_r) * HH + a_kq * 8;

  f32x4 acc[8];
#pragma unroll
  for (int m = 0; m < 8; ++m) acc[m] = (f32x4){0.f, 0.f, 0.f, 0.f};

#pragma unroll
  for (int c = 0; c < 3; ++c) {
    const int kc = c * 256;
    if (c) __syncthreads();  // all waves done reading previous chunk
#pragma unroll
    for (int j = 0; j < 8; ++j)
      gl16(qh + kc + asrc[j], &Alds[(wid * 16 + j * 2) * 256]);
    float b[3][8];
#pragma unroll
    for (int e = 0; e < 4; ++e) {
      reinterpret_cast<float4*>(&b[0][0])[e >> 2] = *reinterpret_cast<const float4*>(bptr + kc + (e & 1) * 4 + 0);
    }
    // (clean explicit prefetch of s=0,1)
    {
      const float4 v0 = *reinterpret_cast<const float4*>(bptr + kc);
      const float4 v1 = *reinterpret_cast<const float4*>(bptr + kc + 4);
      b[0][0] = v0.x; b[0][1] = v0.y; b[0][2] = v0.z; b[0][3] = v0.w;
      b[0][4] = v1.x; b[0][5] = v1.y; b[0][6] = v1.z; b[0][7] = v1.w;
      const float4 v2 = *reinterpret_cast<const float4*>(bptr + kc + 32);
      const float4 v3 = *reinterpret_cast<const float4*>(bptr + kc + 36);
      b[1][0] = v2.x; b[1][1] = v2.y; b[1][2] = v2.z; b[1][3] = v2.w;
      b[1][4] = v3.x; b[1][5] = v3.y; b[1][6] = v3.z; b[1][7] = v3.w;
    }
    __syncthreads();  // A chunk staged (vmcnt drained); b[0],b[1] also in regs
#pragma unroll
    for (int s = 0; s < 8; ++s) {
      if (s < 6) {
        const int nxt = (s + 2) % 3;
        const float4 v0 = *reinterpret_cast<const float4*>(bptr + kc + (s + 2) * 32);
        const float4 v1 = *reinterpret_cast<const float4*>(bptr + kc + (s + 2) * 32 + 4);
        b[nxt][0] = v0.x; b[nxt][1] = v0.y; b[nxt][2] = v0.z; b[nxt][3] = v0.w;
        b[nxt][4] = v1.x; b[nxt][5] = v1.y; b[nxt][6] = v1.z; b[nxt][7] = v1.w;
      }
      const int cur = s % 3;
      short8 bb;
#pragma unroll
      for (int e = 0; e < 8; ++e) bb[e] = (short)f2bf(b[cur][e]);
      const int kq2 = ((s * 4 + a_kq) ^ a_swz) * 8 + a_rowbase;  // ushort offset
#pragma unroll
      for (int m = 0; m < 8; ++m) {
        const short8 aa = *reinterpret_cast<const short8*>(&Alds[m * 4096 + kq2]);
        acc[m] = __builtin_amdgcn_mfma_f32_16x16x32_bf16(aa, bb, acc[m], 0, 0, 0);
      }
    }
  }

  // C[row][col]: row = m*16 + (lane>>4)*4 + r (batch), col = q0 + wid*16 + (lane&15)
  const int ccol = q0 + wid * 16 + a_r;
#pragma unroll
  for (int m = 0; m < 8; ++m)
#pragma unroll
    for (int r = 0; r < 4; ++r)
      C[(size_t)(m * 16 + a_kq * 4 + r) * KQ + ccol] = acc[m][r];
}

// L2-normalize rows of Y and emit bf16.
__global__ __launch_bounds__(256) void l2norm_split(const float* __restrict__ Y,
                                                    unsigned short* __restrict__ qh) {
  const int b = blockIdx.x, tid = threadIdx.x;
  __shared__ float sh[4];
  __shared__ float snorm;
  float ss = 0.f;
  for (int h = tid; h < HH; h += 256) {
    const float v = Y[(size_t)b * HH + h];
    ss = fmaf(v, v, ss);
  }
  for (int o = 32; o; o >>= 1) ss += __shfl_down(ss, o);
  const int lane = tid & 63, wid = tid >> 6;
  if (lane == 0) sh[wid] = ss;
  __syncthreads();
  if (tid == 0) snorm = 1.0f / sqrtf(sh[0] + sh[1] + sh[2] + sh[3]);
  __syncthreads();
  const float rs = snorm;
  for (int h = tid; h < HH; h += 256)
    qh[(size_t)b * HH + h] = f2bf(Y[(size_t)b * HH + h] * rs);
}

__global__ __launch_bounds__(256) void cls_loss_kernel(
    const float* __restrict__ H1, const float* __restrict__ W2,
    const float* __restrict__ b2, const int* __restrict__ labels,
    float* __restrict__ out) {
  const int b = blockIdx.x, tid = threadIdx.x;
  __shared__ float sh0[4], sh1[4];
  float p0 = 0.f, p1 = 0.f;
  for (int h = tid; h < HH; h += 256) {
    const float v = H1[(size_t)b * HH + h];
    p0 = fmaf(v, W2[h * 2 + 0], p0);
    p1 = fmaf(v, W2[h * 2 + 1], p1);
  }
  for (int o = 32; o; o >>= 1) {
    p0 += __shfl_down(p0, o);
    p1 += __shfl_down(p1, o);
  }
  const int lane = tid & 63, wid = tid >> 6;
  if (lane == 0) { sh0[wid] = p0; sh1[wid] = p1; }
  __syncthreads();
  if (tid == 0) {
    const float l0 = sh0[0] + sh0[1] + sh0[2] + sh0[3] + b2[0];
    const float l1 = sh1[0] + sh1[1] + sh1[2] + sh1[3] + b2[1];
    const float mx = fmaxf(l0, l1), mn = fminf(l0, l1);
    const float lse = mx + log1pf(__expf(mn - mx));
    const float ce = lse - (labels[b] ? l1 : l0);
    atomicAdd(out, 0.9f * ce * (1.0f / 128.0f));
  }
}

// Also zeroes out[0] and builds qmask (bit=1 iff label_queue[k]==1).
__global__ __launch_bounds__(1024) void counts_kernel(const int* __restrict__ labels,
                                                      const int* __restrict__ lq,
                                                      int* __restrict__ m_out,
                                                      unsigned* __restrict__ qmask,
                                                      float* __restrict__ out) {
  const int tid = threadIdx.x;
  __shared__ int sh[16];
  __shared__ int has[2];
  unsigned mask = 0u;
  const int base = tid << 5;
#pragma unroll
  for (int j = 0; j < 32; ++j) mask |= (unsigned)(lq[base + j] != 0) << j;
  qmask[tid] = mask;
  int c = __popc(mask);
  for (int o = 32; o; o >>= 1) c += __shfl_down(c, o);
  const int lane = tid & 63, wid = tid >> 6;
  if (tid < 2) has[tid] = 0;
  __syncthreads();
  if (lane == 0) sh[wid] = c;
  if (tid < BB) has[labels[tid]] = 1;
  __syncthreads();
  if (tid == 0) {
    int n1 = 0;
    for (int w = 0; w < 16; ++w) n1 += sh[w];
    const int n0 = KQ - n1;
    int mm = 0x7fffffff;
    if (has[0] && n0 < mm) mm = n0;
    if (has[1] && n1 < mm) mm = n1;
    *m_out = mm;
    out[0] = 0.0f;
  }
}

// Pass A (row read + neg-lse + pos key compaction + pos min/max), then
// histogram radix-select for ranks {25, m-25, m}, then one gather pass.
__global__ __launch_bounds__(1024) void select_kernel(
    const float* __restrict__ Cm, const int* __restrict__ labels,
    const unsigned* __restrict__ qmask, const int* __restrict__ m_ptr,
    float* __restrict__ out) {
  const int b = blockIdx.x;
  const int tid = threadIdx.x;
  const int lane = tid & 63, wid = tid >> 6;
  const float* __restrict__ row = Cm + (size_t)b * KQ;
  const int lab = labels[b];
  const int m = *m_ptr;

  __shared__ __align__(16) unsigned poskeys[PCAP];
  __shared__ unsigned hist[NB + 1];
  __shared__ unsigned cand[3][CCAP];
  __shared__ int candn[3];
  __shared__ float redm[16], reds[16], redmin[16], redmax[16];
  __shared__ unsigned wsum[16];
  __shared__ int abin[3], acnt[3];
  __shared__ unsigned akey[3];
  __shared__ unsigned long long accg;
  __shared__ float gs0, gsm, s_logE, s_vmin, s_vmax;
  __shared__ int s_cnt;

  if (tid == 0) { s_cnt = 0; gs0 = 0.f; gsm = 0.f; accg = 0ull; }
  if (tid < 3) candn[tid] = 0;
  __syncthreads();

  // ---------- Pass A ----------
  const unsigned qm = qmask[tid];
  const unsigned pmask = lab ? qm : ~qm;
  const int base = tid << 5;
  float va[32];
#pragma unroll
  for (int u = 0; u < 8; ++u) {
    const float4 v = *reinterpret_cast<const float4*>(row + base + (u << 2));
    va[(u << 2) + 0] = v.x; va[(u << 2) + 1] = v.y;
    va[(u << 2) + 2] = v.z; va[(u << 2) + 3] = v.w;
  }
  float mneg = -3.0e38f, sneg = 0.f, vmin = 3.0e38f, vmax = -3.0e38f;
#pragma unroll
  for (int j = 0; j < 32; ++j) {
    if ((pmask >> j) & 1u) {
      vmin = fminf(vmin, va[j]);
      vmax = fmaxf(vmax, va[j]);
    } else {
      mneg = fmaxf(mneg, va[j] * TINV);
    }
  }
#pragma unroll
  for (int j = 0; j < 32; ++j) {
    if (!((pmask >> j) & 1u)) sneg += __expf(va[j] * TINV - mneg);
  }
#pragma unroll
  for (int o = 32; o; o >>= 1) {
    const float mo = __shfl_down(mneg, o), so = __shfl_down(sneg, o);
    const float M = fmaxf(mneg, mo);
    sneg = sneg * __expf(mneg - M) + so * __expf(mo - M);
    mneg = M;
    vmin = fminf(vmin, __shfl_down(vmin, o));
    vmax = fmaxf(vmax, __shfl_down(vmax, o));
  }
  if (lane == 0) { redm[wid] = mneg; reds[wid] = sneg; redmin[wid] = vmin; redmax[wid] = vmax; }

  const int np = __popc(pmask);
  unsigned incl = (unsigned)np;
#pragma unroll
  for (int o = 1; o < 64; o <<= 1) {
    const unsigned t = __shfl_up(incl, o);
    if (lane >= o) incl += t;
  }
  const unsigned excl = incl - (unsigned)np;
  const unsigned wtot = __shfl(incl, 63);
  unsigned wbase = 0u;
  if (lane == 63) wbase = (unsigned)atomicAdd(&s_cnt, (int)wtot);
  wbase = __shfl(wbase, 63);
  const int ofs = (int)(wbase + excl);
  if (ofs + np <= PCAP) {
#pragma unroll
    for (int j = 0; j < 32; ++j) {
      if ((pmask >> j) & 1u)
        poskeys[ofs + __popc(pmask & ((1u << j) - 1u))] = f2key(va[j]);
    }
  }
  __syncthreads();

  const int P = s_cnt;
  if (tid == 0) {
    float M = redm[0], S = 0.f;
    float mn = redmin[0], mx = redmax[0];
    for (int w = 1; w < 16; ++w) {
      M = fmaxf(M, redm[w]);
      mn = fminf(mn, redmin[w]);
      mx = fmaxf(mx, redmax[w]);
    }
    for (int w = 0; w < 16; ++w) S += reds[w] * __expf(redm[w] - M);
    s_logE = M + logf(S);
    s_vmin = mn;
    s_vmax = mx;
  }
  if (tid < ((4 - (P & 3)) & 3)) poskeys[P + tid] = 0u;
  for (int i = tid; i < NB + 1; i += 1024) hist[i] = 0u;
  __syncthreads();

  const float cE = s_logE;
  const float vmn = s_vmin;
  const float scale = (float)NB * (1.0f - 1e-6f) / fmaxf(s_vmax - vmn, 1e-30f);
  auto key2bin = [&](unsigned k) {
    int bn = (int)((key2f(k) - vmn) * scale);
    return bn < 0 ? 0 : (bn > NB - 1 ? NB - 1 : bn);
  };

  for (int i = tid; i < P; i += 1024) atomicAdd(&hist[key2bin(poskeys[i])], 1u);
  __syncthreads();

  const int t4 = tid << 2;
  const unsigned h0 = hist[t4], h1 = hist[t4 + 1], h2 = hist[t4 + 2], h3 = hist[t4 + 3];
  const unsigned part = h0 + h1 + h2 + h3;
  unsigned sinc = part;
#pragma unroll
  for (int o = 1; o < 64; o <<= 1) {
    const unsigned t = __shfl_up(sinc, o);
    if (lane >= o) sinc += t;
  }
  if (lane == 63) wsum[wid] = sinc;
  __syncthreads();
  unsigned woff = 0;
  for (int w = 0; w < wid; ++w) woff += wsum[w];
  const unsigned exb = woff + sinc - part;
  hist[t4] = exb; hist[t4 + 1] = exb + h0; hist[t4 + 2] = exb + h0 + h1;
  hist[t4 + 3] = exb + h0 + h1 + h2;
  if (tid == 1023) hist[NB] = exb + part;
  __syncthreads();

  const int rt0 = 25, rt1 = m - 25, rt2 = m;
  const unsigned idx0 = (unsigned)(P - rt0), idx1 = (unsigned)(P - rt1), idx2 = (unsigned)(P - rt2);
#pragma unroll
  for (int i = 0; i < 4; ++i) {
    const int bb = t4 + i;
    const unsigned pb = hist[bb], pb1 = hist[bb + 1];
    if (pb <= idx0 && idx0 < pb1) { abin[0] = bb; acnt[0] = P - (int)pb1; }
    if (pb <= idx1 && idx1 < pb1) { abin[1] = bb; acnt[1] = P - (int)pb1; }
    if (pb <= idx2 && idx2 < pb1) { abin[2] = bb; acnt[2] = P - (int)pb1; }
  }
  __syncthreads();

  const int tb0 = abin[0], tb1 = abin[1], tb2 = abin[2];
  for (int i = tid; i < P; i += 1024) {
    const unsigned k = poskeys[i];
    const int bn = key2bin(k);
    if (bn == tb0) { const int p = atomicAdd(&candn[0], 1); if (p < CCAP) cand[0][p] = k; }
    if (bn == tb1) { const int p = atomicAdd(&candn[1], 1); if (p < CCAP) cand[1][p] = k; }
    if (bn == tb2) { const int p = atomicAdd(&candn[2], 1); if (p < CCAP) cand[2][p] = k; }
  }
  __syncthreads();

  if (wid < 3) {
    const int j = wid;
    const int rts[3] = {rt0, rt1, rt2};
    const int cnt = candn[j] < CCAP ? candn[j] : CCAP;
    const int rr = rts[j] - acnt[j];
    for (int i = lane; i < cnt; i += 64) {
      const unsigned k = cand[j][i];
      int gt = 0, eq = 0;
      for (int q = 0; q < cnt; ++q) {
        const unsigned kq = cand[j][q];
        gt += (kq > k);
        eq += (kq == k);
      }
      if (gt < rr && rr <= gt + eq) akey[j] = k;
    }
  }
  __syncthreads();

  const unsigned a0 = akey[0], a1 = akey[1], a2 = akey[2];
  const int P4c = (P + 3) >> 2;
  const uint4* __restrict__ pk4 = reinterpret_cast<const uint4*>(poskeys);

  float s0 = 0.f, sm = 0.f;
  unsigned q0c = 0, q1c = 0, q2c = 0;
  for (int i = tid; i < P4c; i += 1024) {
    const uint4 kv = pk4[i];
    const unsigned ks[4] = {kv.x, kv.y, kv.z, kv.w};
#pragma unroll
    for (int j = 0; j < 4; ++j) {
      const unsigned k = ks[j];
      if (k > a2) {
        ++q2c;
        const bool top = (k > a0), mid = (k <= a1);
        if (k > a1) ++q1c;
        if (top) ++q0c;
        if (top || mid) {
          const float a = key2f(k) * TINV;
          const float d = cE - a;
          const float fv = fmaxf(d, 0.f) + log1pf(__expf(-fabsf(d)));
          if (top) s0 += fv;
          if (mid) sm += fv;
        }
      }
    }
  }
  unsigned long long pc = (unsigned long long)q0c |
                          ((unsigned long long)q1c << 20) |
                          ((unsigned long long)q2c << 40);
#pragma unroll
  for (int o = 32; o; o >>= 1) {
    s0 += __shfl_down(s0, o);
    sm += __shfl_down(sm, o);
    pc += shfl_down_u64(pc, o);
  }
  if (lane == 0) {
    atomicAdd(&gs0, s0);
    atomicAdd(&gsm, sm);
    atomicAdd(&accg, pc);
  }
  __syncthreads();
  if (tid == 0) {
    const unsigned long long t = accg;
    const float C0 = (float)(unsigned)(t & 0xFFFFFu);
    const float C1 = (float)(unsigned)((t >> 20) & 0xFFFFFu);
    const float C2 = (float)(unsigned)((t >> 40) & 0xFFFFFu);
    auto fval = [&](unsigned kk) {
      const float a = key2f(kk) * TINV;
      const float d = cE - a;
      return fmaxf(d, 0.f) + log1pf(__expf(-fabsf(d)));
    };
    const float f0 = fval(a0), f1 = fval(a1), f2 = fval(a2);
    const float top25 = gs0 + (25.0f - C0) * f0;
    const float mid = gsm + ((float)m - C2) * f2 - ((float)(m - 25) - C1) * f1;
    atomicAdd(out, 0.1f * (top25 + mid) * (1.0f / 6400.0f));
  }
}

extern "C" void kernel_launch(void* const* d_in, const int* in_sizes, int n_in,
                              void* d_out, int out_size, void* d_ws, size_t ws_size,
                              hipStream_t stream) {
  const float* pooled = (const float*)d_in[0];
  const int* labels = (const int*)d_in[1];
  const float* fq = (const float*)d_in[2];
  const int* lq = (const int*)d_in[3];
  const float* cls_dw = (const float*)d_in[4];
  const float* cls_db = (const float*)d_in[5];
  const float* cls_ow = (const float*)d_in[6];
  const float* cls_ob = (const float*)d_in[7];
  const float* con_dw = (const float*)d_in[8];
  const float* con_db = (const float*)d_in[9];
  const float* con_ow = (const float*)d_in[10];
  const float* con_ob = (const float*)d_in[11];
  float* out = (float*)d_out;

  float* ws = (float*)d_ws;
  float* H1 = ws;                                        // 128*768 f32
  float* H2 = ws + 98304;                                // 128*768 f32
  float* Y = ws + 2 * 98304;                             // 128*768 f32
  unsigned short* qh = (unsigned short*)(ws + 3 * 98304); // 128*768 bf16
  float* C = ws + 4 * 98304;                             // 128*32768 f32
  int* mptr = (int*)(ws + 4 * 98304 + (size_t)BB * KQ);
  unsigned* qmask = (unsigned*)(mptr + 1);               // 1024 words

  counts_kernel<<<1, 1024, 0, stream>>>(labels, lq, mptr, qmask, out);
  dense_pair<<<dim3(24, 4, 2), 256, 0, stream>>>(pooled, cls_dw, cls_db, H1,
                                                 con_dw, con_db, H2);
  gemm_bias<<<dim3(24, 4), 256, 0, stream>>>(H2, con_ow, con_ob, Y);
  l2norm_split<<<128, 256, 0, stream>>>(Y, qh);
  cls_loss_kernel<<<128, 256, 0, stream>>>(H1, cls_ow, cls_ob, labels, out);
  cos_gemm_mfma<<<256, 512, 0, stream>>>(qh, fq, C);
  select_kernel<<<128, 1024, 0, stream>>>(C, labels, qmask, mptr, out);
}